// Round 3
// baseline (445.223 us; speedup 1.0000x reference)
//
#include <hip/hip_runtime.h>
#include <math.h>

#define P 65536   // H*W
#define HH 256
#define WW 256

__device__ __forceinline__ float fast_sigmoid(float v) {
    return 1.f / (1.f + __expf(-v));
}
__device__ __forceinline__ float fast_tanh(float a) {
    a = fminf(fmaxf(a, -10.f), 10.f);
    float t = __expf(2.f * a);
    return (t - 1.f) / (t + 1.f);
}

// ---------------------------------------------------------------------------
// Weight-prep: transpose weights to reduction-major layouts in ws, precompute
// mask*w4 table. Layout (float offsets within W):
//   [0,18432)        ue_wt   [ci32][k9][co64]
//   [18432,20736)    aue_wt  [ci64][k9][co4]
//   [20736,39168)    wt1     [n64][k9][m32]
//   [39168,57600)    wt2     [n64][k9][m32]
//   [57600,61696)    s1w1t   [ci64][co64]
//   [61696,65792)    s1w2t   [ci64][co64]
//   [65792,69888)    s2w1t   [ci64][co64]
//   [69888,73984)    s2w2t   [ci64][co64]
//   [73984,75008)    cw1t    [m32][mo32]
//   [75008,76032)    cw2t    [m32][mo32]
//   [76032,78592)    mw      [t10][o4][c64]
__global__ void prep_k(const float* __restrict__ ue_w, const float* __restrict__ aue_w,
                       const float* __restrict__ ua1, const float* __restrict__ ua2,
                       const float* __restrict__ s1w1, const float* __restrict__ s1w2,
                       const float* __restrict__ s2w1, const float* __restrict__ s2w2,
                       const float* __restrict__ cw1, const float* __restrict__ cw2,
                       const float* __restrict__ masks_u, const float* __restrict__ w4,
                       float* __restrict__ W) {
    int i = blockIdx.x * 256 + threadIdx.x;
    if (i < 18432) {                       // ue_w (co64, ci32, 9) -> [ci][k][co]
        int ci = i / 576, r = i % 576, k = r >> 6, co = r & 63;
        W[i] = ue_w[co * 288 + ci * 9 + k];
    } else if (i < 20736) {                // aue_w (co4, ci64, 9) -> [ci][k][co]
        int j = i - 18432;
        int ci = j / 36, r = j % 36, k = r >> 2, co = r & 3;
        W[i] = aue_w[co * 576 + ci * 9 + k];
    } else if (i < 39168) {                // ua1 (m32, n64, 9) -> [n][k][m]
        int j = i - 20736;
        int n = j / 288, r = j % 288, k = r >> 5, m = r & 31;
        W[i] = ua1[m * 576 + n * 9 + k];
    } else if (i < 57600) {
        int j = i - 39168;
        int n = j / 288, r = j % 288, k = r >> 5, m = r & 31;
        W[i] = ua2[m * 576 + n * 9 + k];
    } else if (i < 61696) {                // (co64,ci64) -> [ci][co]
        int j = i - 57600; W[i] = s1w1[(j & 63) * 64 + (j >> 6)];
    } else if (i < 65792) {
        int j = i - 61696; W[i] = s1w2[(j & 63) * 64 + (j >> 6)];
    } else if (i < 69888) {
        int j = i - 65792; W[i] = s2w1[(j & 63) * 64 + (j >> 6)];
    } else if (i < 73984) {
        int j = i - 69888; W[i] = s2w2[(j & 63) * 64 + (j >> 6)];
    } else if (i < 75008) {                // cw1 (mo32,m32) -> [m][mo]
        int j = i - 73984; W[i] = cw1[(j & 31) * 32 + (j >> 5)];
    } else if (i < 76032) {
        int j = i - 75008; W[i] = cw2[(j & 31) * 32 + (j >> 5)];
    } else if (i < 78592) {                // mw[t][o][c] = (mask<0.8)*w4[o][c]
        int j = i - 76032;
        int t = j >> 8, o = (j >> 6) & 3, c = j & 63;
        W[i] = (masks_u[t * 64 + c] < 0.8f) ? w4[o * 64 + c] : 0.f;
    }
}

// ---------------------------------------------------------------------------
// Register-blocked 3x3 conv, pad=1. Weights pre-transposed [ci][k][COTOT],
// read with uniform addresses (SGPR broadcast). Thread: PIX pixels x NCO co.
template<int CIN, int COTOT, int NCO, int PIX, int ACT>
__global__ __launch_bounds__(256) void conv3x3_rb(
        const float* __restrict__ in, const float* __restrict__ wt,
        const float* __restrict__ bias, float* __restrict__ out) {
    const int cob = blockIdx.y * NCO;
    const int pixb = (blockIdx.x * 256 + threadIdx.x) * PIX;
    const int h = pixb >> 8, x0 = pixb & 255;
    float acc[NCO][PIX];
    #pragma unroll
    for (int co = 0; co < NCO; ++co) {
        float b = bias[cob + co];
        #pragma unroll
        for (int j = 0; j < PIX; ++j) acc[co][j] = b;
    }
    #pragma unroll 4
    for (int ci = 0; ci < CIN; ++ci) {
        const float* icp = in + ci * P;
        #pragma unroll
        for (int kh = 0; kh < 3; ++kh) {
            int hh = h + kh - 1;
            if ((unsigned)hh >= 256u) continue;   // wave-uniform
            const float* rp = icp + hh * WW;
            float v[PIX + 2];
            v[0] = (x0 > 0) ? rp[x0 - 1] : 0.f;
            if constexpr (PIX == 4) {
                float4 m = *(const float4*)(rp + x0);
                v[1] = m.x; v[2] = m.y; v[3] = m.z; v[4] = m.w;
            } else {
                float2 m = *(const float2*)(rp + x0);
                v[1] = m.x; v[2] = m.y;
            }
            v[PIX + 1] = (x0 + PIX < 256) ? rp[x0 + PIX] : 0.f;
            #pragma unroll
            for (int kw = 0; kw < 3; ++kw) {
                const float* wp = wt + (ci * 9 + kh * 3 + kw) * COTOT + cob;
                #pragma unroll
                for (int co = 0; co < NCO; ++co) {
                    float wv = wp[co];              // uniform -> s_load
                    #pragma unroll
                    for (int j = 0; j < PIX; ++j)
                        acc[co][j] = fmaf(v[kw + j], wv, acc[co][j]);
                }
            }
        }
    }
    #pragma unroll
    for (int co = 0; co < NCO; ++co) {
        float* op = out + (cob + co) * P + pixb;
        #pragma unroll
        for (int j = 0; j < PIX; ++j) {
            float r = acc[co][j];
            if constexpr (ACT == 2) r = fast_sigmoid(r);
            op[j] = r;
        }
    }
}

// ---------------------------------------------------------------------------
// EU/mean head, mw precomputed in global (uniform s_loads). o split by grid.y.
__global__ __launch_bounds__(256) void xsstats_k(
        const float* __restrict__ x, const float* __restrict__ mw,
        const float* __restrict__ b4, const float* __restrict__ msin,
        float* __restrict__ EU, float* __restrict__ MEAN) {
    int p = blockIdx.x * 256 + threadIdx.x;
    int ob = blockIdx.y * 2;
    float xv[64];
    #pragma unroll
    for (int c = 0; c < 64; ++c) xv[c] = x[c * P + p];
    #pragma unroll
    for (int oi = 0; oi < 2; ++oi) {
        int o = ob + oi;
        float msv = msin[o * P + p];
        float bo  = b4[o];
        float vals[10];
        float s = 0.f;
        #pragma unroll
        for (int t = 0; t < 10; ++t) {
            float a = bo;
            const float* mwp = mw + t * 256 + o * 64;
            #pragma unroll
            for (int c = 0; c < 64; ++c) a = fmaf(mwp[c], xv[c], a);  // s-operand
            float v = fast_tanh(a) + msv;
            vals[t] = v;
            s += v;
        }
        float m = s * 0.1f;
        MEAN[o * P + p] = m;
        float var = 0.f;
        #pragma unroll
        for (int t = 0; t < 10; ++t) { float d = vals[t] - m; var = fmaf(d, d, var); }
        EU[o * P + p] = var * (1.0f / 9.0f);
    }
}

// ---------------------------------------------------------------------------
// Fused spatial-gate chain (scalar weights, no LDS).
__global__ __launch_bounds__(256) void spa_fused_k(
        const float* __restrict__ U,
        const float* __restrict__ w0, const float* __restrict__ b0,
        const float* __restrict__ w1, const float* __restrict__ b1,
        const float* __restrict__ w2, const float* __restrict__ b2,
        float* __restrict__ spat, int flip) {
    int p = blockIdx.x * 256 + threadIdx.x;
    int h = p >> 8, x0 = p & 255;
    float u[4][9];
    #pragma unroll
    for (int ci = 0; ci < 4; ++ci) {
        const float* up = U + ci * P;
        #pragma unroll
        for (int kh = 0; kh < 3; ++kh) {
            int hh = h + kh - 1;
            bool hok = (unsigned)hh < 256u;
            #pragma unroll
            for (int kw = 0; kw < 3; ++kw) {
                int wx = x0 + kw - 1;
                bool ok = hok && (unsigned)wx < 256u;
                float v = ok ? up[hh * WW + wx] : 0.f;
                if (flip && ok) v = 1.f - v;
                u[ci][kh * 3 + kw] = v;
            }
        }
    }
    float a1[9];
    #pragma unroll
    for (int co = 0; co < 9; ++co) {
        float s = b0[co];
        #pragma unroll
        for (int ci = 0; ci < 4; ++ci)
            #pragma unroll
            for (int k = 0; k < 9; ++k)
                s = fmaf(u[ci][k], w0[co * 36 + ci * 9 + k], s);
        a1[co] = fmaxf(s, 0.f);
    }
    float a2[9];
    #pragma unroll
    for (int co = 0; co < 9; ++co) {
        float s = b1[co];
        #pragma unroll
        for (int ci = 0; ci < 9; ++ci) s = fmaf(a1[ci], w1[co * 9 + ci], s);
        a2[co] = fmaxf(s, 0.f);
    }
    #pragma unroll
    for (int co = 0; co < 9; ++co) {
        float s = b2[co];
        #pragma unroll
        for (int ci = 0; ci < 9; ++ci) s = fmaf(a2[ci], w2[co * 9 + ci], s);
        spat[co * P + p] = fast_sigmoid(s);
    }
}

// ---------------------------------------------------------------------------
// Fused spectral-gate MLP (w1t/w2t pre-transposed [ci][co], scalar weights).
__global__ __launch_bounds__(256, 1) void spe_fused_k(
        const float* __restrict__ U, int flip,
        const float* __restrict__ w0, const float* __restrict__ b0,
        const float* __restrict__ w1t, const float* __restrict__ b1,
        const float* __restrict__ w2t, const float* __restrict__ b2,
        float* __restrict__ spec) {
    int p = blockIdx.x * 256 + threadIdx.x;
    float u[4];
    #pragma unroll
    for (int ci = 0; ci < 4; ++ci) {
        float v = U[ci * P + p];
        u[ci] = flip ? 1.f - v : v;
    }
    float h1[64];
    #pragma unroll
    for (int co = 0; co < 64; ++co) {
        float s = b0[co];
        #pragma unroll
        for (int ci = 0; ci < 4; ++ci) s = fmaf(u[ci], w0[co * 4 + ci], s);
        h1[co] = fmaxf(s, 0.f);
    }
    float h2[64];
    #pragma unroll
    for (int co = 0; co < 64; ++co) h2[co] = b1[co];
    #pragma unroll
    for (int ci = 0; ci < 64; ++ci) {
        float hv = h1[ci];
        const float* wr = w1t + ci * 64;
        #pragma unroll
        for (int co = 0; co < 64; ++co) h2[co] = fmaf(hv, wr[co], h2[co]);
    }
    #pragma unroll
    for (int co = 0; co < 64; ++co) h2[co] = fmaxf(h2[co], 0.f);
    float h3[64];
    #pragma unroll
    for (int co = 0; co < 64; ++co) h3[co] = b2[co];
    #pragma unroll
    for (int ci = 0; ci < 64; ++ci) {
        float hv = h2[ci];
        const float* wr = w2t + ci * 64;
        #pragma unroll
        for (int co = 0; co < 64; ++co) h3[co] = fmaf(hv, wr[co], h3[co]);
    }
    #pragma unroll
    for (int co = 0; co < 64; ++co)
        spec[co * P + p] = fast_sigmoid(h3[co]);
}

// ---------------------------------------------------------------------------
// uaconv v3: 1024 threads = 256 px x 4 n-groups; scalar weights [n][k][m];
// LDS cross-group reduction; fused 1x1 conv (cwt [m][mo]) + lrelu.
__global__ __launch_bounds__(1024) void uaconv3_k(
        const float* __restrict__ xa, const float* __restrict__ xb,
        const float* __restrict__ spec, const float* __restrict__ spat,
        const float* __restrict__ wt, const float* __restrict__ cwt,
        const float* __restrict__ cb, float* __restrict__ fout) {
    __shared__ float red[8 * 4 * 256];   // [m-oct][g][px]  32 KB
    const int tid = threadIdx.x;
    const int pxl = tid & 255;
    const int g   = __builtin_amdgcn_readfirstlane(tid >> 8);  // wave-uniform
    const int p   = blockIdx.x * 256 + pxl;
    const int h = p >> 8, x0 = p & 255;
    const float* xbase = (g < 2) ? (xa + g * 16 * P) : (xb + (g - 2) * 16 * P);
    const int nbase = g * 16;

    float sv[9];
    #pragma unroll
    for (int k = 0; k < 9; ++k) sv[k] = spat[k * P + p];
    float acc[32];
    #pragma unroll
    for (int m = 0; m < 32; ++m) acc[m] = 0.f;

    for (int nl = 0; nl < 16; ++nl) {
        const float* xc = xbase + nl * P;
        float s = spec[(nbase + nl) * P + p];
        float q[9];
        #pragma unroll
        for (int kh = 0; kh < 3; ++kh) {
            int hh = h + kh - 1;
            bool hok = (unsigned)hh < 256u;
            #pragma unroll
            for (int kw = 0; kw < 3; ++kw) {
                int wx = x0 + kw - 1;
                float v = (hok && (unsigned)wx < 256u) ? xc[hh * WW + wx] : 0.f;
                q[kh * 3 + kw] = v * s * sv[kh * 3 + kw];
            }
        }
        const float* wn = wt + (nbase + nl) * 288;
        #pragma unroll
        for (int k = 0; k < 9; ++k) {
            float qk = q[k];
            const float* wp = wn + k * 32;
            #pragma unroll
            for (int m = 0; m < 32; ++m)
                acc[m] = fmaf(qk, wp[m], acc[m]);   // s-operand FMA
        }
    }

    // cross-group reduce + fused 1x1 + lrelu; mo-range = [g*8, g*8+8)
    float fo[8];
    #pragma unroll
    for (int jo = 0; jo < 8; ++jo) fo[jo] = cb[g * 8 + jo];
    #pragma unroll
    for (int r = 0; r < 4; ++r) {
        if (r) __syncthreads();
        #pragma unroll
        for (int j = 0; j < 8; ++j)
            red[(j * 4 + g) * 256 + pxl] = acc[r * 8 + j];
        __syncthreads();
        #pragma unroll
        for (int j = 0; j < 8; ++j) {
            int m = r * 8 + j;
            float y = red[(j * 4 + 0) * 256 + pxl] + red[(j * 4 + 1) * 256 + pxl]
                    + red[(j * 4 + 2) * 256 + pxl] + red[(j * 4 + 3) * 256 + pxl];
            const float* cwp = cwt + m * 32 + g * 8;
            #pragma unroll
            for (int jo = 0; jo < 8; ++jo)
                fo[jo] = fmaf(y, cwp[jo], fo[jo]);
        }
    }
    #pragma unroll
    for (int jo = 0; jo < 8; ++jo) {
        float v = fo[jo];
        fout[(g * 8 + jo) * P + p] = v > 0.f ? v : 0.2f * v;
    }
}

// ---------------------------------------------------------------------------
extern "C" void kernel_launch(void* const* d_in, const int* in_sizes, int n_in,
                              void* d_out, int out_size, void* d_ws, size_t ws_size,
                              hipStream_t stream) {
    const float* F1        = (const float*)d_in[0];
    const float* ms        = (const float*)d_in[1];
    const float* pan       = (const float*)d_in[2];
    const float* masks_u   = (const float*)d_in[3];
    const float* ue_conv_w = (const float*)d_in[4];
    const float* ue_conv_b = (const float*)d_in[5];
    const float* ue_out_w  = (const float*)d_in[6];
    const float* ue_out_b  = (const float*)d_in[7];
    const float* ue_aue_w  = (const float*)d_in[8];
    const float* ue_aue_b  = (const float*)d_in[9];
    const float* conv1_w   = (const float*)d_in[10];
    const float* conv1_b   = (const float*)d_in[11];
    const float* conv2_w   = (const float*)d_in[12];
    const float* conv2_b   = (const float*)d_in[13];
    const float* spa1_w0 = (const float*)d_in[14];
    const float* spa1_b0 = (const float*)d_in[15];
    const float* spa1_w1 = (const float*)d_in[16];
    const float* spa1_b1 = (const float*)d_in[17];
    const float* spa1_w2 = (const float*)d_in[18];
    const float* spa1_b2 = (const float*)d_in[19];
    const float* spe1_w0 = (const float*)d_in[20];
    const float* spe1_b0 = (const float*)d_in[21];
    const float* spe1_w1 = (const float*)d_in[22];
    const float* spe1_b1 = (const float*)d_in[23];
    const float* spe1_w2 = (const float*)d_in[24];
    const float* spe1_b2 = (const float*)d_in[25];
    const float* ua1_w   = (const float*)d_in[26];
    const float* spa2_w0 = (const float*)d_in[27];
    const float* spa2_b0 = (const float*)d_in[28];
    const float* spa2_w1 = (const float*)d_in[29];
    const float* spa2_b1 = (const float*)d_in[30];
    const float* spa2_w2 = (const float*)d_in[31];
    const float* spa2_b2 = (const float*)d_in[32];
    const float* spe2_w0 = (const float*)d_in[33];
    const float* spe2_b0 = (const float*)d_in[34];
    const float* spe2_w1 = (const float*)d_in[35];
    const float* spe2_b1 = (const float*)d_in[36];
    const float* spe2_w2 = (const float*)d_in[37];
    const float* spe2_b2 = (const float*)d_in[38];
    const float* ua2_w   = (const float*)d_in[39];

    float* out  = (float*)d_out;
    float* AU   = out;             // 4*P
    float* EU   = out + 4 * P;     // 4*P
    float* MEAN = out + 8 * P;     // 4*P
    float* FOUT = out + 12 * P;    // 32*P

    float* ws   = (float*)d_ws;
    float* x    = ws;              // 64P
    float* spec = ws + 64 * P;     // 64P
    float* spat = ws + 128 * P;    // 9P
    float* f2   = ws + 137 * P;    // 32P
    float* W    = ws + 169 * P;    // 78592 floats of transposed weights
    float* ue_wt  = W;
    float* aue_wt = W + 18432;
    float* wt1    = W + 20736;
    float* wt2    = W + 39168;
    float* s1w1t  = W + 57600;
    float* s1w2t  = W + 61696;
    float* s2w1t  = W + 65792;
    float* s2w2t  = W + 69888;
    float* cw1t   = W + 73984;
    float* cw2t   = W + 75008;
    float* mw     = W + 76032;

    dim3 blk(256);

    prep_k<<<dim3(307), blk, 0, stream>>>(ue_conv_w, ue_aue_w, ua1_w, ua2_w,
                                          spe1_w1, spe1_w2, spe2_w1, spe2_w2,
                                          conv1_w, conv2_w, masks_u, ue_out_w, W);

    // x = conv3x3(F_1; 32->64)
    conv3x3_rb<32, 64, 4, 4, 0><<<dim3(64, 16), blk, 0, stream>>>(F1, ue_wt, ue_conv_b, x);
    // EU / mean
    xsstats_k<<<dim3(256, 2), blk, 0, stream>>>(x, mw, ue_out_b, ms, EU, MEAN);
    // AU = sigmoid(conv3x3(x; 64->4))
    conv3x3_rb<64, 4, 1, 2, 2><<<dim3(128, 4), blk, 0, stream>>>(x, aue_wt, ue_aue_b, AU);

    // ---- uaconv 1 (U = EU, inputs F1 || pan), fused conv1 -> f2 ----
    spa_fused_k<<<dim3(256), blk, 0, stream>>>(EU, spa1_w0, spa1_b0, spa1_w1, spa1_b1,
                                               spa1_w2, spa1_b2, spat, 0);
    spe_fused_k<<<dim3(256), blk, 0, stream>>>(EU, 0, spe1_w0, spe1_b0, s1w1t, spe1_b1,
                                               s1w2t, spe1_b2, spec);
    uaconv3_k<<<dim3(256), dim3(1024), 0, stream>>>(F1, pan, spec, spat, wt1, cw1t, conv1_b, f2);

    // ---- uaconv 2 (U = 1-EU, inputs F1 || F_2), fused conv2 -> FOUT ----
    spa_fused_k<<<dim3(256), blk, 0, stream>>>(EU, spa2_w0, spa2_b0, spa2_w1, spa2_b1,
                                               spa2_w2, spa2_b2, spat, 1);
    spe_fused_k<<<dim3(256), blk, 0, stream>>>(EU, 1, spe2_w0, spe2_b0, s2w1t, spe2_b1,
                                               s2w2t, spe2_b2, spec);
    uaconv3_k<<<dim3(256), dim3(1024), 0, stream>>>(F1, f2, spec, spat, wt2, cw2t, conv2_b, FOUT);
}

// Round 4
// 313.645 us; speedup vs baseline: 1.4195x; 1.4195x over previous
//
#include <hip/hip_runtime.h>
#include <math.h>

#define P 65536   // H*W
#define HH 256
#define WW 256

__device__ __forceinline__ float fast_sigmoid(float v) {
    return 1.f / (1.f + __expf(-v));
}
__device__ __forceinline__ float fast_tanh(float a) {
    a = fminf(fmaxf(a, -10.f), 10.f);
    float t = __expf(2.f * a);
    return (t - 1.f) / (t + 1.f);
}

// ---------------------------------------------------------------------------
// Weight-prep: transpose weights to reduction-major layouts in ws, precompute
// mask*w4 table. Layout (float offsets within W):
//   [0,18432)        ue_wt   [ci32][k9][co64]
//   [18432,20736)    aue_wt  [ci64][k9][co4]
//   [20736,39168)    wt1     [n64][k9][m32]
//   [39168,57600)    wt2     [n64][k9][m32]
//   [57600,61696)    s1w1t   [ci64][co64]
//   [61696,65792)    s1w2t   [ci64][co64]
//   [65792,69888)    s2w1t   [ci64][co64]
//   [69888,73984)    s2w2t   [ci64][co64]
//   [73984,75008)    cw1t    [m32][mo32]
//   [75008,76032)    cw2t    [m32][mo32]
//   [76032,78592)    mw      [t10][o4][c64]
__global__ void prep_k(const float* __restrict__ ue_w, const float* __restrict__ aue_w,
                       const float* __restrict__ ua1, const float* __restrict__ ua2,
                       const float* __restrict__ s1w1, const float* __restrict__ s1w2,
                       const float* __restrict__ s2w1, const float* __restrict__ s2w2,
                       const float* __restrict__ cw1, const float* __restrict__ cw2,
                       const float* __restrict__ masks_u, const float* __restrict__ w4,
                       float* __restrict__ W) {
    int i = blockIdx.x * 256 + threadIdx.x;
    if (i < 18432) {                       // ue_w (co64, ci32, 9) -> [ci][k][co]
        int ci = i / 576, r = i % 576, k = r >> 6, co = r & 63;
        W[i] = ue_w[co * 288 + ci * 9 + k];
    } else if (i < 20736) {                // aue_w (co4, ci64, 9) -> [ci][k][co]
        int j = i - 18432;
        int ci = j / 36, r = j % 36, k = r >> 2, co = r & 3;
        W[i] = aue_w[co * 576 + ci * 9 + k];
    } else if (i < 39168) {                // ua1 (m32, n64, 9) -> [n][k][m]
        int j = i - 20736;
        int n = j / 288, r = j % 288, k = r >> 5, m = r & 31;
        W[i] = ua1[m * 576 + n * 9 + k];
    } else if (i < 57600) {
        int j = i - 39168;
        int n = j / 288, r = j % 288, k = r >> 5, m = r & 31;
        W[i] = ua2[m * 576 + n * 9 + k];
    } else if (i < 61696) {                // (co64,ci64) -> [ci][co]
        int j = i - 57600; W[i] = s1w1[(j & 63) * 64 + (j >> 6)];
    } else if (i < 65792) {
        int j = i - 61696; W[i] = s1w2[(j & 63) * 64 + (j >> 6)];
    } else if (i < 69888) {
        int j = i - 65792; W[i] = s2w1[(j & 63) * 64 + (j >> 6)];
    } else if (i < 73984) {
        int j = i - 69888; W[i] = s2w2[(j & 63) * 64 + (j >> 6)];
    } else if (i < 75008) {                // cw1 (mo32,m32) -> [m][mo]
        int j = i - 73984; W[i] = cw1[(j & 31) * 32 + (j >> 5)];
    } else if (i < 76032) {
        int j = i - 75008; W[i] = cw2[(j & 31) * 32 + (j >> 5)];
    } else if (i < 78592) {                // mw[t][o][c] = (mask<0.8)*w4[o][c]
        int j = i - 76032;
        int t = j >> 8, o = (j >> 6) & 3, c = j & 63;
        W[i] = (masks_u[t * 64 + c] < 0.8f) ? w4[o * 64 + c] : 0.f;
    }
}

// ---------------------------------------------------------------------------
// Register-blocked 3x3 conv, pad=1. Weights pre-transposed [ci][k][COTOT],
// read with uniform addresses (SGPR broadcast). Thread: PIX pixels x NCO co.
template<int CIN, int COTOT, int NCO, int PIX, int ACT>
__global__ __launch_bounds__(256) void conv3x3_rb(
        const float* __restrict__ in, const float* __restrict__ wt,
        const float* __restrict__ bias, float* __restrict__ out) {
    const int cob = blockIdx.y * NCO;
    const int pixb = (blockIdx.x * 256 + threadIdx.x) * PIX;
    const int h = pixb >> 8, x0 = pixb & 255;
    float acc[NCO][PIX];
    #pragma unroll
    for (int co = 0; co < NCO; ++co) {
        float b = bias[cob + co];
        #pragma unroll
        for (int j = 0; j < PIX; ++j) acc[co][j] = b;
    }
    #pragma unroll 4
    for (int ci = 0; ci < CIN; ++ci) {
        const float* icp = in + ci * P;
        #pragma unroll
        for (int kh = 0; kh < 3; ++kh) {
            int hh = h + kh - 1;
            if ((unsigned)hh >= 256u) continue;   // wave-uniform
            const float* rp = icp + hh * WW;
            float v[PIX + 2];
            v[0] = (x0 > 0) ? rp[x0 - 1] : 0.f;
            if constexpr (PIX == 4) {
                float4 m = *(const float4*)(rp + x0);
                v[1] = m.x; v[2] = m.y; v[3] = m.z; v[4] = m.w;
            } else {
                float2 m = *(const float2*)(rp + x0);
                v[1] = m.x; v[2] = m.y;
            }
            v[PIX + 1] = (x0 + PIX < 256) ? rp[x0 + PIX] : 0.f;
            #pragma unroll
            for (int kw = 0; kw < 3; ++kw) {
                const float* wp = wt + (ci * 9 + kh * 3 + kw) * COTOT + cob;
                #pragma unroll
                for (int co = 0; co < NCO; ++co) {
                    float wv = wp[co];              // uniform -> s_load
                    #pragma unroll
                    for (int j = 0; j < PIX; ++j)
                        acc[co][j] = fmaf(v[kw + j], wv, acc[co][j]);
                }
            }
        }
    }
    #pragma unroll
    for (int co = 0; co < NCO; ++co) {
        float* op = out + (cob + co) * P + pixb;
        #pragma unroll
        for (int j = 0; j < PIX; ++j) {
            float r = acc[co][j];
            if constexpr (ACT == 2) r = fast_sigmoid(r);
            op[j] = r;
        }
    }
}

// ---------------------------------------------------------------------------
// EU/mean head, mw precomputed in global (uniform s_loads). One o per block.y.
__global__ __launch_bounds__(256) void xsstats_k(
        const float* __restrict__ x, const float* __restrict__ mw,
        const float* __restrict__ b4, const float* __restrict__ msin,
        float* __restrict__ EU, float* __restrict__ MEAN) {
    int p = blockIdx.x * 256 + threadIdx.x;
    int o = blockIdx.y;
    float xv[64];
    #pragma unroll
    for (int c = 0; c < 64; ++c) xv[c] = x[c * P + p];
    float msv = msin[o * P + p];
    float bo  = b4[o];
    float vals[10];
    float s = 0.f;
    #pragma unroll
    for (int t = 0; t < 10; ++t) {
        float a = bo;
        const float* mwp = mw + t * 256 + o * 64;
        #pragma unroll
        for (int c = 0; c < 64; ++c) a = fmaf(mwp[c], xv[c], a);  // s-operand
        float v = fast_tanh(a) + msv;
        vals[t] = v;
        s += v;
    }
    float m = s * 0.1f;
    MEAN[o * P + p] = m;
    float var = 0.f;
    #pragma unroll
    for (int t = 0; t < 10; ++t) { float d = vals[t] - m; var = fmaf(d, d, var); }
    EU[o * P + p] = var * (1.0f / 9.0f);
}

// ---------------------------------------------------------------------------
// Fused spatial-gate chain (scalar weights, no LDS).
__global__ __launch_bounds__(256) void spa_fused_k(
        const float* __restrict__ U,
        const float* __restrict__ w0, const float* __restrict__ b0,
        const float* __restrict__ w1, const float* __restrict__ b1,
        const float* __restrict__ w2, const float* __restrict__ b2,
        float* __restrict__ spat, int flip) {
    int p = blockIdx.x * 256 + threadIdx.x;
    int h = p >> 8, x0 = p & 255;
    float u[4][9];
    #pragma unroll
    for (int ci = 0; ci < 4; ++ci) {
        const float* up = U + ci * P;
        #pragma unroll
        for (int kh = 0; kh < 3; ++kh) {
            int hh = h + kh - 1;
            bool hok = (unsigned)hh < 256u;
            #pragma unroll
            for (int kw = 0; kw < 3; ++kw) {
                int wx = x0 + kw - 1;
                bool ok = hok && (unsigned)wx < 256u;
                float v = ok ? up[hh * WW + wx] : 0.f;
                if (flip && ok) v = 1.f - v;
                u[ci][kh * 3 + kw] = v;
            }
        }
    }
    float a1[9];
    #pragma unroll
    for (int co = 0; co < 9; ++co) {
        float s = b0[co];
        #pragma unroll
        for (int ci = 0; ci < 4; ++ci)
            #pragma unroll
            for (int k = 0; k < 9; ++k)
                s = fmaf(u[ci][k], w0[co * 36 + ci * 9 + k], s);
        a1[co] = fmaxf(s, 0.f);
    }
    float a2[9];
    #pragma unroll
    for (int co = 0; co < 9; ++co) {
        float s = b1[co];
        #pragma unroll
        for (int ci = 0; ci < 9; ++ci) s = fmaf(a1[ci], w1[co * 9 + ci], s);
        a2[co] = fmaxf(s, 0.f);
    }
    #pragma unroll
    for (int co = 0; co < 9; ++co) {
        float s = b2[co];
        #pragma unroll
        for (int ci = 0; ci < 9; ++ci) s = fmaf(a2[ci], w2[co * 9 + ci], s);
        spat[co * P + p] = fast_sigmoid(s);
    }
}

// ---------------------------------------------------------------------------
// Spectral-gate MLP v2: block = 64 px x 4 wave-groups; each group computes 16
// of the 64 h2/h3 channels; h2 shared via LDS [ci][px] (conflict-free).
// h1 computed on the fly (no h1 array -> low VGPR). Weights [ci][co] -> s_load.
__global__ __launch_bounds__(256) void spe2_k(
        const float* __restrict__ U, int flip,
        const float* __restrict__ w0, const float* __restrict__ b0,
        const float* __restrict__ w1t, const float* __restrict__ b1,
        const float* __restrict__ w2t, const float* __restrict__ b2,
        float* __restrict__ spec) {
    __shared__ float h2s[64 * 64];   // [ci][px] 16 KB
    const int tid = threadIdx.x;
    const int pxg = tid & 63;
    const int g   = __builtin_amdgcn_readfirstlane(tid >> 6);  // wave index
    const int cb  = g * 16;
    const int p   = blockIdx.x * 64 + pxg;

    float u[4];
    #pragma unroll
    for (int ci = 0; ci < 4; ++ci) {
        float v = U[ci * P + p];
        u[ci] = flip ? 1.f - v : v;
    }
    float h2[16];
    #pragma unroll
    for (int j = 0; j < 16; ++j) h2[j] = b1[cb + j];
    #pragma unroll 8
    for (int ci = 0; ci < 64; ++ci) {
        // h1[ci] on the fly
        float s = b0[ci];
        #pragma unroll
        for (int k = 0; k < 4; ++k) s = fmaf(u[k], w0[ci * 4 + k], s);
        float hv = fmaxf(s, 0.f);
        const float* wr = w1t + ci * 64 + cb;      // uniform -> s_load
        #pragma unroll
        for (int j = 0; j < 16; ++j) h2[j] = fmaf(hv, wr[j], h2[j]);
    }
    #pragma unroll
    for (int j = 0; j < 16; ++j)
        h2s[(cb + j) * 64 + pxg] = fmaxf(h2[j], 0.f);
    __syncthreads();

    float h3[16];
    #pragma unroll
    for (int j = 0; j < 16; ++j) h3[j] = b2[cb + j];
    #pragma unroll 8
    for (int ci = 0; ci < 64; ++ci) {
        float hv = h2s[ci * 64 + pxg];
        const float* wr = w2t + ci * 64 + cb;      // uniform -> s_load
        #pragma unroll
        for (int j = 0; j < 16; ++j) h3[j] = fmaf(hv, wr[j], h3[j]);
    }
    #pragma unroll
    for (int j = 0; j < 16; ++j)
        spec[(cb + j) * P + p] = fast_sigmoid(h3[j]);
}

// ---------------------------------------------------------------------------
// uaconv v3: 1024 threads = 256 px x 4 n-groups; scalar weights [n][k][m];
// LDS cross-group reduction; fused 1x1 conv (cwt [m][mo]) + lrelu.
__global__ __launch_bounds__(1024) void uaconv3_k(
        const float* __restrict__ xa, const float* __restrict__ xb,
        const float* __restrict__ spec, const float* __restrict__ spat,
        const float* __restrict__ wt, const float* __restrict__ cwt,
        const float* __restrict__ cb, float* __restrict__ fout) {
    __shared__ float red[8 * 4 * 256];   // [m-oct][g][px]  32 KB
    const int tid = threadIdx.x;
    const int pxl = tid & 255;
    const int g   = __builtin_amdgcn_readfirstlane(tid >> 8);  // wave-uniform
    const int p   = blockIdx.x * 256 + pxl;
    const int h = p >> 8, x0 = p & 255;
    const float* xbase = (g < 2) ? (xa + g * 16 * P) : (xb + (g - 2) * 16 * P);
    const int nbase = g * 16;

    float sv[9];
    #pragma unroll
    for (int k = 0; k < 9; ++k) sv[k] = spat[k * P + p];
    float acc[32];
    #pragma unroll
    for (int m = 0; m < 32; ++m) acc[m] = 0.f;

    for (int nl = 0; nl < 16; ++nl) {
        const float* xc = xbase + nl * P;
        float s = spec[(nbase + nl) * P + p];
        float q[9];
        #pragma unroll
        for (int kh = 0; kh < 3; ++kh) {
            int hh = h + kh - 1;
            bool hok = (unsigned)hh < 256u;
            #pragma unroll
            for (int kw = 0; kw < 3; ++kw) {
                int wx = x0 + kw - 1;
                float v = (hok && (unsigned)wx < 256u) ? xc[hh * WW + wx] : 0.f;
                q[kh * 3 + kw] = v * s * sv[kh * 3 + kw];
            }
        }
        const float* wn = wt + (nbase + nl) * 288;
        #pragma unroll
        for (int k = 0; k < 9; ++k) {
            float qk = q[k];
            const float* wp = wn + k * 32;
            #pragma unroll
            for (int m = 0; m < 32; ++m)
                acc[m] = fmaf(qk, wp[m], acc[m]);   // s-operand FMA
        }
    }

    // cross-group reduce + fused 1x1 + lrelu; mo-range = [g*8, g*8+8)
    float fo[8];
    #pragma unroll
    for (int jo = 0; jo < 8; ++jo) fo[jo] = cb[g * 8 + jo];
    #pragma unroll
    for (int r = 0; r < 4; ++r) {
        if (r) __syncthreads();
        #pragma unroll
        for (int j = 0; j < 8; ++j)
            red[(j * 4 + g) * 256 + pxl] = acc[r * 8 + j];
        __syncthreads();
        #pragma unroll
        for (int j = 0; j < 8; ++j) {
            int m = r * 8 + j;
            float y = red[(j * 4 + 0) * 256 + pxl] + red[(j * 4 + 1) * 256 + pxl]
                    + red[(j * 4 + 2) * 256 + pxl] + red[(j * 4 + 3) * 256 + pxl];
            const float* cwp = cwt + m * 32 + g * 8;
            #pragma unroll
            for (int jo = 0; jo < 8; ++jo)
                fo[jo] = fmaf(y, cwp[jo], fo[jo]);
        }
    }
    #pragma unroll
    for (int jo = 0; jo < 8; ++jo) {
        float v = fo[jo];
        fout[(g * 8 + jo) * P + p] = v > 0.f ? v : 0.2f * v;
    }
}

// ---------------------------------------------------------------------------
extern "C" void kernel_launch(void* const* d_in, const int* in_sizes, int n_in,
                              void* d_out, int out_size, void* d_ws, size_t ws_size,
                              hipStream_t stream) {
    const float* F1        = (const float*)d_in[0];
    const float* ms        = (const float*)d_in[1];
    const float* pan       = (const float*)d_in[2];
    const float* masks_u   = (const float*)d_in[3];
    const float* ue_conv_w = (const float*)d_in[4];
    const float* ue_conv_b = (const float*)d_in[5];
    const float* ue_out_w  = (const float*)d_in[6];
    const float* ue_out_b  = (const float*)d_in[7];
    const float* ue_aue_w  = (const float*)d_in[8];
    const float* ue_aue_b  = (const float*)d_in[9];
    const float* conv1_w   = (const float*)d_in[10];
    const float* conv1_b   = (const float*)d_in[11];
    const float* conv2_w   = (const float*)d_in[12];
    const float* conv2_b   = (const float*)d_in[13];
    const float* spa1_w0 = (const float*)d_in[14];
    const float* spa1_b0 = (const float*)d_in[15];
    const float* spa1_w1 = (const float*)d_in[16];
    const float* spa1_b1 = (const float*)d_in[17];
    const float* spa1_w2 = (const float*)d_in[18];
    const float* spa1_b2 = (const float*)d_in[19];
    const float* spe1_w0 = (const float*)d_in[20];
    const float* spe1_b0 = (const float*)d_in[21];
    const float* spe1_w1 = (const float*)d_in[22];
    const float* spe1_b1 = (const float*)d_in[23];
    const float* spe1_w2 = (const float*)d_in[24];
    const float* spe1_b2 = (const float*)d_in[25];
    const float* ua1_w   = (const float*)d_in[26];
    const float* spa2_w0 = (const float*)d_in[27];
    const float* spa2_b0 = (const float*)d_in[28];
    const float* spa2_w1 = (const float*)d_in[29];
    const float* spa2_b1 = (const float*)d_in[30];
    const float* spa2_w2 = (const float*)d_in[31];
    const float* spa2_b2 = (const float*)d_in[32];
    const float* spe2_w0 = (const float*)d_in[33];
    const float* spe2_b0 = (const float*)d_in[34];
    const float* spe2_w1 = (const float*)d_in[35];
    const float* spe2_b1 = (const float*)d_in[36];
    const float* spe2_w2 = (const float*)d_in[37];
    const float* spe2_b2 = (const float*)d_in[38];
    const float* ua2_w   = (const float*)d_in[39];

    float* out  = (float*)d_out;
    float* AU   = out;             // 4*P
    float* EU   = out + 4 * P;     // 4*P
    float* MEAN = out + 8 * P;     // 4*P
    float* FOUT = out + 12 * P;    // 32*P

    float* ws   = (float*)d_ws;
    float* x    = ws;              // 64P
    float* spec = ws + 64 * P;     // 64P
    float* spat = ws + 128 * P;    // 9P
    float* f2   = ws + 137 * P;    // 32P
    float* W    = ws + 169 * P;    // 78592 floats of transposed weights
    float* ue_wt  = W;
    float* aue_wt = W + 18432;
    float* wt1    = W + 20736;
    float* wt2    = W + 39168;
    float* s1w1t  = W + 57600;
    float* s1w2t  = W + 61696;
    float* s2w1t  = W + 65792;
    float* s2w2t  = W + 69888;
    float* cw1t   = W + 73984;
    float* cw2t   = W + 75008;
    float* mw     = W + 76032;

    dim3 blk(256);

    prep_k<<<dim3(307), blk, 0, stream>>>(ue_conv_w, ue_aue_w, ua1_w, ua2_w,
                                          spe1_w1, spe1_w2, spe2_w1, spe2_w2,
                                          conv1_w, conv2_w, masks_u, ue_out_w, W);

    // x = conv3x3(F_1; 32->64)
    conv3x3_rb<32, 64, 4, 4, 0><<<dim3(64, 16), blk, 0, stream>>>(F1, ue_wt, ue_conv_b, x);
    // EU / mean
    xsstats_k<<<dim3(256, 4), blk, 0, stream>>>(x, mw, ue_out_b, ms, EU, MEAN);
    // AU = sigmoid(conv3x3(x; 64->4))
    conv3x3_rb<64, 4, 1, 2, 2><<<dim3(128, 4), blk, 0, stream>>>(x, aue_wt, ue_aue_b, AU);

    // ---- uaconv 1 (U = EU, inputs F1 || pan), fused conv1 -> f2 ----
    spa_fused_k<<<dim3(256), blk, 0, stream>>>(EU, spa1_w0, spa1_b0, spa1_w1, spa1_b1,
                                               spa1_w2, spa1_b2, spat, 0);
    spe2_k<<<dim3(1024), blk, 0, stream>>>(EU, 0, spe1_w0, spe1_b0, s1w1t, spe1_b1,
                                           s1w2t, spe1_b2, spec);
    uaconv3_k<<<dim3(256), dim3(1024), 0, stream>>>(F1, pan, spec, spat, wt1, cw1t, conv1_b, f2);

    // ---- uaconv 2 (U = 1-EU, inputs F1 || F_2), fused conv2 -> FOUT ----
    spa_fused_k<<<dim3(256), blk, 0, stream>>>(EU, spa2_w0, spa2_b0, spa2_w1, spa2_b1,
                                               spa2_w2, spa2_b2, spat, 1);
    spe2_k<<<dim3(1024), blk, 0, stream>>>(EU, 1, spe2_w0, spe2_b0, s2w1t, spe2_b1,
                                           s2w2t, spe2_b2, spec);
    uaconv3_k<<<dim3(256), dim3(1024), 0, stream>>>(F1, f2, spec, spat, wt2, cw2t, conv2_b, FOUT);
}

// Round 5
// 248.663 us; speedup vs baseline: 1.7905x; 1.2613x over previous
//
#include <hip/hip_runtime.h>
#include <math.h>

#define P 65536   // H*W
#define HH 256
#define WW 256

__device__ __forceinline__ float fast_sigmoid(float v) {
    return 1.f / (1.f + __expf(-v));
}
__device__ __forceinline__ float fast_tanh(float a) {
    a = fminf(fmaxf(a, -10.f), 10.f);
    float t = __expf(2.f * a);
    return (t - 1.f) / (t + 1.f);
}

// ---------------------------------------------------------------------------
// Weight-prep: transpose weights to reduction-major layouts in ws, precompute
// mask*w4 table. Layout (float offsets within W):
//   [0,18432)        ue_wt   [ci32][k9][co64]
//   [18432,20736)    aue_wt  [ci64][k9][co4]
//   [20736,39168)    wt1     [n64][k9][m32]
//   [39168,57600)    wt2     [n64][k9][m32]
//   [57600,61696)    s1w1t   [ci64][co64]
//   [61696,65792)    s1w2t   [ci64][co64]
//   [65792,69888)    s2w1t   [ci64][co64]
//   [69888,73984)    s2w2t   [ci64][co64]
//   [73984,75008)    cw1t    [m32][mo32]
//   [75008,76032)    cw2t    [m32][mo32]
//   [76032,78592)    mw      [t10][o4][c64]
__global__ void prep_k(const float* __restrict__ ue_w, const float* __restrict__ aue_w,
                       const float* __restrict__ ua1, const float* __restrict__ ua2,
                       const float* __restrict__ s1w1, const float* __restrict__ s1w2,
                       const float* __restrict__ s2w1, const float* __restrict__ s2w2,
                       const float* __restrict__ cw1, const float* __restrict__ cw2,
                       const float* __restrict__ masks_u, const float* __restrict__ w4,
                       float* __restrict__ W) {
    int i = blockIdx.x * 256 + threadIdx.x;
    if (i < 18432) {                       // ue_w (co64, ci32, 9) -> [ci][k][co]
        int ci = i / 576, r = i % 576, k = r >> 6, co = r & 63;
        W[i] = ue_w[co * 288 + ci * 9 + k];
    } else if (i < 20736) {                // aue_w (co4, ci64, 9) -> [ci][k][co]
        int j = i - 18432;
        int ci = j / 36, r = j % 36, k = r >> 2, co = r & 3;
        W[i] = aue_w[co * 576 + ci * 9 + k];
    } else if (i < 39168) {                // ua1 (m32, n64, 9) -> [n][k][m]
        int j = i - 20736;
        int n = j / 288, r = j % 288, k = r >> 5, m = r & 31;
        W[i] = ua1[m * 576 + n * 9 + k];
    } else if (i < 57600) {
        int j = i - 39168;
        int n = j / 288, r = j % 288, k = r >> 5, m = r & 31;
        W[i] = ua2[m * 576 + n * 9 + k];
    } else if (i < 61696) {                // (co64,ci64) -> [ci][co]
        int j = i - 57600; W[i] = s1w1[(j & 63) * 64 + (j >> 6)];
    } else if (i < 65792) {
        int j = i - 61696; W[i] = s1w2[(j & 63) * 64 + (j >> 6)];
    } else if (i < 69888) {
        int j = i - 65792; W[i] = s2w1[(j & 63) * 64 + (j >> 6)];
    } else if (i < 73984) {
        int j = i - 69888; W[i] = s2w2[(j & 63) * 64 + (j >> 6)];
    } else if (i < 75008) {                // cw1 (mo32,m32) -> [m][mo]
        int j = i - 73984; W[i] = cw1[(j & 31) * 32 + (j >> 5)];
    } else if (i < 76032) {
        int j = i - 75008; W[i] = cw2[(j & 31) * 32 + (j >> 5)];
    } else if (i < 78592) {                // mw[t][o][c] = (mask<0.8)*w4[o][c]
        int j = i - 76032;
        int t = j >> 8, o = (j >> 6) & 3, c = j & 63;
        W[i] = (masks_u[t * 64 + c] < 0.8f) ? w4[o * 64 + c] : 0.f;
    }
}

// ---------------------------------------------------------------------------
// Register-blocked 3x3 conv, pad=1. Weights pre-transposed [ci][k][COTOT],
// read with uniform addresses (SGPR broadcast). Thread: PIX pixels x NCO co.
template<int CIN, int COTOT, int NCO, int PIX, int ACT>
__global__ __launch_bounds__(256) void conv3x3_rb(
        const float* __restrict__ in, const float* __restrict__ wt,
        const float* __restrict__ bias, float* __restrict__ out) {
    const int cob = blockIdx.y * NCO;
    const int pixb = (blockIdx.x * 256 + threadIdx.x) * PIX;
    const int h = pixb >> 8, x0 = pixb & 255;
    float acc[NCO][PIX];
    #pragma unroll
    for (int co = 0; co < NCO; ++co) {
        float b = bias[cob + co];
        #pragma unroll
        for (int j = 0; j < PIX; ++j) acc[co][j] = b;
    }
    #pragma unroll 4
    for (int ci = 0; ci < CIN; ++ci) {
        const float* icp = in + ci * P;
        #pragma unroll
        for (int kh = 0; kh < 3; ++kh) {
            int hh = h + kh - 1;
            if ((unsigned)hh >= 256u) continue;   // wave-uniform
            const float* rp = icp + hh * WW;
            float v[PIX + 2];
            v[0] = (x0 > 0) ? rp[x0 - 1] : 0.f;
            if constexpr (PIX == 4) {
                float4 m = *(const float4*)(rp + x0);
                v[1] = m.x; v[2] = m.y; v[3] = m.z; v[4] = m.w;
            } else {
                float2 m = *(const float2*)(rp + x0);
                v[1] = m.x; v[2] = m.y;
            }
            v[PIX + 1] = (x0 + PIX < 256) ? rp[x0 + PIX] : 0.f;
            #pragma unroll
            for (int kw = 0; kw < 3; ++kw) {
                const float* wp = wt + (ci * 9 + kh * 3 + kw) * COTOT + cob;
                #pragma unroll
                for (int co = 0; co < NCO; ++co) {
                    float wv = wp[co];              // uniform -> s_load
                    #pragma unroll
                    for (int j = 0; j < PIX; ++j)
                        acc[co][j] = fmaf(v[kw + j], wv, acc[co][j]);
                }
            }
        }
    }
    #pragma unroll
    for (int co = 0; co < NCO; ++co) {
        float* op = out + (cob + co) * P + pixb;
        #pragma unroll
        for (int j = 0; j < PIX; ++j) {
            float r = acc[co][j];
            if constexpr (ACT == 2) r = fast_sigmoid(r);
            op[j] = r;
        }
    }
}

// ---------------------------------------------------------------------------
// Fused head: AU = sigmoid(conv3x3(x;64->4)), EU/MEAN = var/mean of xs.
// Block = 64 px x 4 wave-groups; group g loads ci in [16g,16g+16) (3x3 halo),
// contributes aue partials (LDS-reduced), stores center x values to LDS;
// then group g computes o=g statistics with x pulled LDS->regs.
__global__ __launch_bounds__(256) void head_k(
        const float* __restrict__ x, const float* __restrict__ aue_wt,
        const float* __restrict__ aue_b, const float* __restrict__ mw,
        const float* __restrict__ b4, const float* __restrict__ msin,
        float* __restrict__ AU, float* __restrict__ EU, float* __restrict__ MEAN) {
    __shared__ float cs[64][65];      // [px][ci] pad-65: bank = (px+ci)%32
    __shared__ float pr[4][4][64];    // [co][g][px]
    const int tid = threadIdx.x;
    const int pxg = tid & 63;
    const int g   = __builtin_amdgcn_readfirstlane(tid >> 6);
    const int p   = blockIdx.x * 64 + pxg;
    const int h = p >> 8, x0 = p & 255;
    const int cib = g * 16;

    float pa[4] = {0.f, 0.f, 0.f, 0.f};
    #pragma unroll 4
    for (int cl = 0; cl < 16; ++cl) {
        const int ci = cib + cl;
        const float* xc = x + ci * P;
        float v[9];
        #pragma unroll
        for (int kh = 0; kh < 3; ++kh) {
            int hh = h + kh - 1;
            bool hok = (unsigned)hh < 256u;
            const float* rp = xc + hh * WW;
            v[kh * 3 + 0] = (hok && x0 > 0)   ? rp[x0 - 1] : 0.f;
            v[kh * 3 + 1] = hok               ? rp[x0]     : 0.f;
            v[kh * 3 + 2] = (hok && x0 < 255) ? rp[x0 + 1] : 0.f;
        }
        cs[pxg][ci] = v[4];
        const float* wp = aue_wt + ci * 36;   // [k9][co4], uniform -> s_load
        #pragma unroll
        for (int k = 0; k < 9; ++k) {
            float vv = v[k];
            #pragma unroll
            for (int co = 0; co < 4; ++co)
                pa[co] = fmaf(vv, wp[k * 4 + co], pa[co]);
        }
    }
    #pragma unroll
    for (int co = 0; co < 4; ++co) pr[co][g][pxg] = pa[co];
    __syncthreads();

    // AU for co = g
    {
        float s = aue_b[g] + pr[g][0][pxg] + pr[g][1][pxg]
                           + pr[g][2][pxg] + pr[g][3][pxg];
        AU[g * P + p] = fast_sigmoid(s);
    }

    // xsstats for o = g: pull all 64 center values LDS -> regs (2-way banks, free)
    float xv[64];
    #pragma unroll
    for (int c = 0; c < 64; ++c) xv[c] = cs[pxg][c];
    float msv = msin[g * P + p];
    float bo  = b4[g];
    float vals[10];
    float s = 0.f;
    #pragma unroll
    for (int t = 0; t < 10; ++t) {
        float a = bo;
        const float* mwp = mw + t * 256 + g * 64;   // uniform -> s_load
        #pragma unroll
        for (int c = 0; c < 64; ++c) a = fmaf(mwp[c], xv[c], a);
        float v = fast_tanh(a) + msv;
        vals[t] = v;
        s += v;
    }
    float m = s * 0.1f;
    MEAN[g * P + p] = m;
    float var = 0.f;
    #pragma unroll
    for (int t = 0; t < 10; ++t) { float d = vals[t] - m; var = fmaf(d, d, var); }
    EU[g * P + p] = var * (1.0f / 9.0f);
}

// ---------------------------------------------------------------------------
// Fused spatial-gate chain (scalar weights, no LDS).
__global__ __launch_bounds__(256) void spa_fused_k(
        const float* __restrict__ U,
        const float* __restrict__ w0, const float* __restrict__ b0,
        const float* __restrict__ w1, const float* __restrict__ b1,
        const float* __restrict__ w2, const float* __restrict__ b2,
        float* __restrict__ spat, int flip) {
    int p = blockIdx.x * 256 + threadIdx.x;
    int h = p >> 8, x0 = p & 255;
    float u[4][9];
    #pragma unroll
    for (int ci = 0; ci < 4; ++ci) {
        const float* up = U + ci * P;
        #pragma unroll
        for (int kh = 0; kh < 3; ++kh) {
            int hh = h + kh - 1;
            bool hok = (unsigned)hh < 256u;
            #pragma unroll
            for (int kw = 0; kw < 3; ++kw) {
                int wx = x0 + kw - 1;
                bool ok = hok && (unsigned)wx < 256u;
                float v = ok ? up[hh * WW + wx] : 0.f;
                if (flip && ok) v = 1.f - v;
                u[ci][kh * 3 + kw] = v;
            }
        }
    }
    float a1[9];
    #pragma unroll
    for (int co = 0; co < 9; ++co) {
        float s = b0[co];
        #pragma unroll
        for (int ci = 0; ci < 4; ++ci)
            #pragma unroll
            for (int k = 0; k < 9; ++k)
                s = fmaf(u[ci][k], w0[co * 36 + ci * 9 + k], s);
        a1[co] = fmaxf(s, 0.f);
    }
    float a2[9];
    #pragma unroll
    for (int co = 0; co < 9; ++co) {
        float s = b1[co];
        #pragma unroll
        for (int ci = 0; ci < 9; ++ci) s = fmaf(a1[ci], w1[co * 9 + ci], s);
        a2[co] = fmaxf(s, 0.f);
    }
    #pragma unroll
    for (int co = 0; co < 9; ++co) {
        float s = b2[co];
        #pragma unroll
        for (int ci = 0; ci < 9; ++ci) s = fmaf(a2[ci], w2[co * 9 + ci], s);
        spat[co * P + p] = fast_sigmoid(s);
    }
}

// ---------------------------------------------------------------------------
// Spectral-gate MLP v2: block = 64 px x 4 wave-groups; each group computes 16
// of the 64 h2/h3 channels; h2 shared via LDS [ci][px] (conflict-free).
__global__ __launch_bounds__(256) void spe2_k(
        const float* __restrict__ U, int flip,
        const float* __restrict__ w0, const float* __restrict__ b0,
        const float* __restrict__ w1t, const float* __restrict__ b1,
        const float* __restrict__ w2t, const float* __restrict__ b2,
        float* __restrict__ spec) {
    __shared__ float h2s[64 * 64];   // [ci][px] 16 KB
    const int tid = threadIdx.x;
    const int pxg = tid & 63;
    const int g   = __builtin_amdgcn_readfirstlane(tid >> 6);  // wave index
    const int cb  = g * 16;
    const int p   = blockIdx.x * 64 + pxg;

    float u[4];
    #pragma unroll
    for (int ci = 0; ci < 4; ++ci) {
        float v = U[ci * P + p];
        u[ci] = flip ? 1.f - v : v;
    }
    float h2[16];
    #pragma unroll
    for (int j = 0; j < 16; ++j) h2[j] = b1[cb + j];
    #pragma unroll 8
    for (int ci = 0; ci < 64; ++ci) {
        // h1[ci] on the fly
        float s = b0[ci];
        #pragma unroll
        for (int k = 0; k < 4; ++k) s = fmaf(u[k], w0[ci * 4 + k], s);
        float hv = fmaxf(s, 0.f);
        const float* wr = w1t + ci * 64 + cb;      // uniform -> s_load
        #pragma unroll
        for (int j = 0; j < 16; ++j) h2[j] = fmaf(hv, wr[j], h2[j]);
    }
    #pragma unroll
    for (int j = 0; j < 16; ++j)
        h2s[(cb + j) * 64 + pxg] = fmaxf(h2[j], 0.f);
    __syncthreads();

    float h3[16];
    #pragma unroll
    for (int j = 0; j < 16; ++j) h3[j] = b2[cb + j];
    #pragma unroll 8
    for (int ci = 0; ci < 64; ++ci) {
        float hv = h2s[ci * 64 + pxg];
        const float* wr = w2t + ci * 64 + cb;      // uniform -> s_load
        #pragma unroll
        for (int j = 0; j < 16; ++j) h3[j] = fmaf(hv, wr[j], h3[j]);
    }
    #pragma unroll
    for (int j = 0; j < 16; ++j)
        spec[(cb + j) * P + p] = fast_sigmoid(h3[j]);
}

// ---------------------------------------------------------------------------
// uaconv v4: 256 threads = 64 px x 4 n-groups; scalar weights [n][k][m];
// LDS cross-group reduction (8 KB); fused 1x1 conv (cwt [m][mo]) + lrelu.
__global__ __launch_bounds__(256) void uaconv4_k(
        const float* __restrict__ xa, const float* __restrict__ xb,
        const float* __restrict__ spec, const float* __restrict__ spat,
        const float* __restrict__ wt, const float* __restrict__ cwt,
        const float* __restrict__ cb, float* __restrict__ fout) {
    __shared__ float red[8 * 4 * 64];   // [m-oct][g][px]  8 KB
    const int tid = threadIdx.x;
    const int pxl = tid & 63;
    const int g   = __builtin_amdgcn_readfirstlane(tid >> 6);  // wave-uniform
    const int p   = blockIdx.x * 64 + pxl;
    const int h = p >> 8, x0 = p & 255;
    const float* xbase = (g < 2) ? (xa + g * 16 * P) : (xb + (g - 2) * 16 * P);
    const int nbase = g * 16;

    float sv[9];
    #pragma unroll
    for (int k = 0; k < 9; ++k) sv[k] = spat[k * P + p];
    float acc[32];
    #pragma unroll
    for (int m = 0; m < 32; ++m) acc[m] = 0.f;

    for (int nl = 0; nl < 16; ++nl) {
        const float* xc = xbase + nl * P;
        float s = spec[(nbase + nl) * P + p];
        float q[9];
        #pragma unroll
        for (int kh = 0; kh < 3; ++kh) {
            int hh = h + kh - 1;
            bool hok = (unsigned)hh < 256u;
            #pragma unroll
            for (int kw = 0; kw < 3; ++kw) {
                int wx = x0 + kw - 1;
                float v = (hok && (unsigned)wx < 256u) ? xc[hh * WW + wx] : 0.f;
                q[kh * 3 + kw] = v * s * sv[kh * 3 + kw];
            }
        }
        const float* wn = wt + (nbase + nl) * 288;
        #pragma unroll
        for (int k = 0; k < 9; ++k) {
            float qk = q[k];
            const float* wp = wn + k * 32;
            #pragma unroll
            for (int m = 0; m < 32; ++m)
                acc[m] = fmaf(qk, wp[m], acc[m]);   // s-operand FMA
        }
    }

    // cross-group reduce + fused 1x1 + lrelu; mo-range = [g*8, g*8+8)
    float fo[8];
    #pragma unroll
    for (int jo = 0; jo < 8; ++jo) fo[jo] = cb[g * 8 + jo];
    #pragma unroll
    for (int r = 0; r < 4; ++r) {
        if (r) __syncthreads();
        #pragma unroll
        for (int j = 0; j < 8; ++j)
            red[(j * 4 + g) * 64 + pxl] = acc[r * 8 + j];
        __syncthreads();
        #pragma unroll
        for (int j = 0; j < 8; ++j) {
            int m = r * 8 + j;
            float y = red[(j * 4 + 0) * 64 + pxl] + red[(j * 4 + 1) * 64 + pxl]
                    + red[(j * 4 + 2) * 64 + pxl] + red[(j * 4 + 3) * 64 + pxl];
            const float* cwp = cwt + m * 32 + g * 8;
            #pragma unroll
            for (int jo = 0; jo < 8; ++jo)
                fo[jo] = fmaf(y, cwp[jo], fo[jo]);
        }
    }
    #pragma unroll
    for (int jo = 0; jo < 8; ++jo) {
        float v = fo[jo];
        fout[(g * 8 + jo) * P + p] = v > 0.f ? v : 0.2f * v;
    }
}

// ---------------------------------------------------------------------------
extern "C" void kernel_launch(void* const* d_in, const int* in_sizes, int n_in,
                              void* d_out, int out_size, void* d_ws, size_t ws_size,
                              hipStream_t stream) {
    const float* F1        = (const float*)d_in[0];
    const float* ms        = (const float*)d_in[1];
    const float* pan       = (const float*)d_in[2];
    const float* masks_u   = (const float*)d_in[3];
    const float* ue_conv_w = (const float*)d_in[4];
    const float* ue_conv_b = (const float*)d_in[5];
    const float* ue_out_w  = (const float*)d_in[6];
    const float* ue_out_b  = (const float*)d_in[7];
    const float* ue_aue_w  = (const float*)d_in[8];
    const float* ue_aue_b  = (const float*)d_in[9];
    const float* conv1_w   = (const float*)d_in[10];
    const float* conv1_b   = (const float*)d_in[11];
    const float* conv2_w   = (const float*)d_in[12];
    const float* conv2_b   = (const float*)d_in[13];
    const float* spa1_w0 = (const float*)d_in[14];
    const float* spa1_b0 = (const float*)d_in[15];
    const float* spa1_w1 = (const float*)d_in[16];
    const float* spa1_b1 = (const float*)d_in[17];
    const float* spa1_w2 = (const float*)d_in[18];
    const float* spa1_b2 = (const float*)d_in[19];
    const float* spe1_w0 = (const float*)d_in[20];
    const float* spe1_b0 = (const float*)d_in[21];
    const float* spe1_w1 = (const float*)d_in[22];
    const float* spe1_b1 = (const float*)d_in[23];
    const float* spe1_w2 = (const float*)d_in[24];
    const float* spe1_b2 = (const float*)d_in[25];
    const float* ua1_w   = (const float*)d_in[26];
    const float* spa2_w0 = (const float*)d_in[27];
    const float* spa2_b0 = (const float*)d_in[28];
    const float* spa2_w1 = (const float*)d_in[29];
    const float* spa2_b1 = (const float*)d_in[30];
    const float* spa2_w2 = (const float*)d_in[31];
    const float* spa2_b2 = (const float*)d_in[32];
    const float* spe2_w0 = (const float*)d_in[33];
    const float* spe2_b0 = (const float*)d_in[34];
    const float* spe2_w1 = (const float*)d_in[35];
    const float* spe2_b1 = (const float*)d_in[36];
    const float* spe2_w2 = (const float*)d_in[37];
    const float* spe2_b2 = (const float*)d_in[38];
    const float* ua2_w   = (const float*)d_in[39];

    float* out  = (float*)d_out;
    float* AU   = out;             // 4*P
    float* EU   = out + 4 * P;     // 4*P
    float* MEAN = out + 8 * P;     // 4*P
    float* FOUT = out + 12 * P;    // 32*P

    float* ws   = (float*)d_ws;
    float* x    = ws;              // 64P
    float* spec = ws + 64 * P;     // 64P
    float* spat = ws + 128 * P;    // 9P
    float* f2   = ws + 137 * P;    // 32P
    float* W    = ws + 169 * P;    // 78592 floats of transposed weights
    float* ue_wt  = W;
    float* aue_wt = W + 18432;
    float* wt1    = W + 20736;
    float* wt2    = W + 39168;
    float* s1w1t  = W + 57600;
    float* s1w2t  = W + 61696;
    float* s2w1t  = W + 65792;
    float* s2w2t  = W + 69888;
    float* cw1t   = W + 73984;
    float* cw2t   = W + 75008;
    float* mw     = W + 76032;

    dim3 blk(256);

    prep_k<<<dim3(307), blk, 0, stream>>>(ue_conv_w, ue_aue_w, ua1_w, ua2_w,
                                          spe1_w1, spe1_w2, spe2_w1, spe2_w2,
                                          conv1_w, conv2_w, masks_u, ue_out_w, W);

    // x = conv3x3(F_1; 32->64)
    conv3x3_rb<32, 64, 8, 4, 0><<<dim3(64, 8), blk, 0, stream>>>(F1, ue_wt, ue_conv_b, x);
    // Fused head: AU + EU + MEAN
    head_k<<<dim3(1024), blk, 0, stream>>>(x, aue_wt, ue_aue_b, mw, ue_out_b, ms,
                                           AU, EU, MEAN);

    // ---- uaconv 1 (U = EU, inputs F1 || pan), fused conv1 -> f2 ----
    spa_fused_k<<<dim3(256), blk, 0, stream>>>(EU, spa1_w0, spa1_b0, spa1_w1, spa1_b1,
                                               spa1_w2, spa1_b2, spat, 0);
    spe2_k<<<dim3(1024), blk, 0, stream>>>(EU, 0, spe1_w0, spe1_b0, s1w1t, spe1_b1,
                                           s1w2t, spe1_b2, spec);
    uaconv4_k<<<dim3(1024), blk, 0, stream>>>(F1, pan, spec, spat, wt1, cw1t, conv1_b, f2);

    // ---- uaconv 2 (U = 1-EU, inputs F1 || F_2), fused conv2 -> FOUT ----
    spa_fused_k<<<dim3(256), blk, 0, stream>>>(EU, spa2_w0, spa2_b0, spa2_w1, spa2_b1,
                                               spa2_w2, spa2_b2, spat, 1);
    spe2_k<<<dim3(1024), blk, 0, stream>>>(EU, 1, spe2_w0, spe2_b0, s2w1t, spe2_b1,
                                           s2w2t, spe2_b2, spec);
    uaconv4_k<<<dim3(1024), blk, 0, stream>>>(F1, f2, spec, spat, wt2, cw2t, conv2_b, FOUT);
}

// Round 6
// 193.730 us; speedup vs baseline: 2.2982x; 1.2836x over previous
//
#include <hip/hip_runtime.h>
#include <math.h>

#define P 65536   // H*W
#define HH 256
#define WW 256

typedef __attribute__((ext_vector_type(8))) short bf16x8;
typedef __attribute__((ext_vector_type(4))) float f32x4;

__device__ __forceinline__ float fast_sigmoid(float v) {
    return 1.f / (1.f + __expf(-v));
}
__device__ __forceinline__ float fast_tanh(float a) {
    a = fminf(fmaxf(a, -10.f), 10.f);
    float t = __expf(2.f * a);
    return (t - 1.f) / (t + 1.f);
}
__device__ __forceinline__ ushort f2bf(float f) {
    unsigned u = __float_as_uint(f);
    unsigned r = (u + 0x7fffu + ((u >> 16) & 1u)) >> 16;
    return (ushort)r;
}

// ---------------------------------------------------------------------------
// Weight-prep. Layout (float offsets within W):
//   [0,18432)        (unused legacy ue_wt)
//   [18432,20736)    aue_wt  [ci64][k9][co4]
//   [20736,39168)    wt1     [n64][k9][m32]
//   [39168,57600)    wt2     [n64][k9][m32]
//   [57600,61696)    s1w1t   [ci64][co64]
//   [61696,65792)    s1w2t   [ci64][co64]
//   [65792,69888)    s2w1t   [ci64][co64]
//   [69888,73984)    s2w2t   [ci64][co64]
//   [73984,75008)    cw1t    [m32][mo32]
//   [75008,76032)    cw2t    [m32][mo32]
//   [76032,78592)    mw      [t10][o4][c64]
// plus bf16 MFMA weights (ushort* wbfu): i in [78592*?,...) handled below:
//   wbfu[18432]: [ct4][kp9][n16][ci32] bf16 of ue_conv_w
__global__ void prep_k(const float* __restrict__ ue_w, const float* __restrict__ aue_w,
                       const float* __restrict__ ua1, const float* __restrict__ ua2,
                       const float* __restrict__ s1w1, const float* __restrict__ s1w2,
                       const float* __restrict__ s2w1, const float* __restrict__ s2w2,
                       const float* __restrict__ cw1, const float* __restrict__ cw2,
                       const float* __restrict__ masks_u, const float* __restrict__ w4,
                       float* __restrict__ W, ushort* __restrict__ wbfu) {
    int i = blockIdx.x * 256 + threadIdx.x;
    if (i < 18432) {                       // legacy (unused)
        int ci = i / 576, r = i % 576, k = r >> 6, co = r & 63;
        W[i] = ue_w[co * 288 + ci * 9 + k];
    } else if (i < 20736) {                // aue_w (co4, ci64, 9) -> [ci][k][co]
        int j = i - 18432;
        int ci = j / 36, r = j % 36, k = r >> 2, co = r & 3;
        W[i] = aue_w[co * 576 + ci * 9 + k];
    } else if (i < 39168) {                // ua1 (m32, n64, 9) -> [n][k][m]
        int j = i - 20736;
        int n = j / 288, r = j % 288, k = r >> 5, m = r & 31;
        W[i] = ua1[m * 576 + n * 9 + k];
    } else if (i < 57600) {
        int j = i - 39168;
        int n = j / 288, r = j % 288, k = r >> 5, m = r & 31;
        W[i] = ua2[m * 576 + n * 9 + k];
    } else if (i < 61696) {                // (co64,ci64) -> [ci][co]
        int j = i - 57600; W[i] = s1w1[(j & 63) * 64 + (j >> 6)];
    } else if (i < 65792) {
        int j = i - 61696; W[i] = s1w2[(j & 63) * 64 + (j >> 6)];
    } else if (i < 69888) {
        int j = i - 65792; W[i] = s2w1[(j & 63) * 64 + (j >> 6)];
    } else if (i < 73984) {
        int j = i - 69888; W[i] = s2w2[(j & 63) * 64 + (j >> 6)];
    } else if (i < 75008) {                // cw1 (mo32,m32) -> [m][mo]
        int j = i - 73984; W[i] = cw1[(j & 31) * 32 + (j >> 5)];
    } else if (i < 76032) {
        int j = i - 75008; W[i] = cw2[(j & 31) * 32 + (j >> 5)];
    } else if (i < 78592) {                // mw[t][o][c] = (mask<0.8)*w4[o][c]
        int j = i - 76032;
        int t = j >> 8, o = (j >> 6) & 3, c = j & 63;
        W[i] = (masks_u[t * 64 + c] < 0.8f) ? w4[o * 64 + c] : 0.f;
    } else if (i < 97024) {                // wbfu: [ct][kp][n][ci] bf16
        int j = i - 78592;
        int ct = j / 4608, r1 = j % 4608;
        int kp = r1 / 512, r2 = r1 % 512;
        int n = r2 >> 5, ci = r2 & 31;
        wbfu[j] = f2bf(ue_w[(ct * 16 + n) * 288 + ci * 9 + kp]);
    }
}

// ---------------------------------------------------------------------------
// F1 (NCHW f32) -> xbf (NHWC bf16): xbf[p*32+ci]
__global__ __launch_bounds__(256) void tobf_k(const float* __restrict__ F1,
                                              ushort* __restrict__ xbf) {
    int p = blockIdx.x * 256 + threadIdx.x;
    unsigned pk[16];
    #pragma unroll
    for (int c = 0; c < 16; ++c) {
        float a = F1[(2 * c) * P + p];
        float b = F1[(2 * c + 1) * P + p];
        pk[c] = (unsigned)f2bf(a) | ((unsigned)f2bf(b) << 16);
    }
    uint4* dst = (uint4*)(xbf + (size_t)p * 32);
    #pragma unroll
    for (int q = 0; q < 4; ++q)
        dst[q] = make_uint4(pk[4 * q], pk[4 * q + 1], pk[4 * q + 2], pk[4 * q + 3]);
}

// ---------------------------------------------------------------------------
// ue conv (32->64, 3x3, pad=1) as MFMA implicit GEMM.
// Block = 4 waves; wave wv owns co-tile [wv*16, wv*16+16); 4 strips of 16 px.
// A: xbf NHWC bf16 (lane: px=l&15, ci=(l>>4)*8+j, one 16B load).
// B: wbfu [ct][kp][n][ci] (lane: n=l&15, ci-chunk=(l>>4)*8, 16B load), held in regs.
// C epilogue: LDS transpose -> coalesced NCHW f32 stores.
__global__ __launch_bounds__(256) void conv_ue_mfma(
        const ushort* __restrict__ xbf, const ushort* __restrict__ wbfu,
        const float* __restrict__ bias, float* __restrict__ out) {
    __shared__ float tls[4][272];           // per-wave 16px x 17(co pad)
    const int tid  = threadIdx.x;
    const int lane = tid & 63;
    const int wv   = __builtin_amdgcn_readfirstlane(tid >> 6);
    const int lrow = lane & 15;
    const int kg   = lane >> 4;

    bf16x8 zf;
    #pragma unroll
    for (int z = 0; z < 8; ++z) zf[z] = 0;

    bf16x8 Bf[9];
    const ushort* wb = wbfu + wv * 4608;
    #pragma unroll
    for (int kp = 0; kp < 9; ++kp)
        Bf[kp] = *(const bf16x8*)(wb + kp * 512 + lrow * 32 + kg * 8);

    const float bco = bias[wv * 16 + lrow];
    float* tw = tls[wv];

    for (int si = 0; si < 4; ++si) {
        const int s   = blockIdx.x * 4 + si;
        const int row = s >> 4;
        const int cb  = (s & 15) << 4;
        const int pb  = s << 4;
        f32x4 acc = {bco, bco, bco, bco};
        #pragma unroll
        for (int dh = -1; dh <= 1; ++dh) {
            if ((unsigned)(row + dh) >= 256u) continue;   // wave-uniform
            #pragma unroll
            for (int dw = -1; dw <= 1; ++dw) {
                const bool kill = (dw == -1 && cb == 0 && lrow == 0) ||
                                  (dw == 1 && cb == 240 && lrow == 15);
                const int apx = kill ? pb : (pb + dh * 256 + dw + lrow);
                bf16x8 Af = *(const bf16x8*)(xbf + (size_t)apx * 32 + kg * 8);
                if (kill) Af = zf;
                acc = __builtin_amdgcn_mfma_f32_16x16x32_bf16(
                          Af, Bf[(dh + 1) * 3 + (dw + 1)], acc, 0, 0, 0);
            }
        }
        // C: col(co)=lane&15, row(px)=kg*4+j  ->  LDS transpose -> coalesced store
        #pragma unroll
        for (int j = 0; j < 4; ++j)
            tw[(kg * 4 + j) * 17 + lrow] = acc[j];
        asm volatile("s_waitcnt lgkmcnt(0)" ::: "memory");
        #pragma unroll
        for (int it = 0; it < 4; ++it) {
            const int co = kg + it * 4;
            out[(wv * 16 + co) * P + pb + lrow] = tw[lrow * 17 + co];
        }
        asm volatile("s_waitcnt lgkmcnt(0)" ::: "memory");
    }
}

// ---------------------------------------------------------------------------
// Fused head: AU = sigmoid(conv3x3(x;64->4)), EU/MEAN = var/mean of xs.
__global__ __launch_bounds__(256) void head_k(
        const float* __restrict__ x, const float* __restrict__ aue_wt,
        const float* __restrict__ aue_b, const float* __restrict__ mw,
        const float* __restrict__ b4, const float* __restrict__ msin,
        float* __restrict__ AU, float* __restrict__ EU, float* __restrict__ MEAN) {
    __shared__ float cs[64][65];      // [px][ci] pad-65
    __shared__ float pr[4][4][64];    // [co][g][px]
    const int tid = threadIdx.x;
    const int pxg = tid & 63;
    const int g   = __builtin_amdgcn_readfirstlane(tid >> 6);
    const int p   = blockIdx.x * 64 + pxg;
    const int h = p >> 8, x0 = p & 255;
    const int cib = g * 16;

    float pa[4] = {0.f, 0.f, 0.f, 0.f};
    #pragma unroll 4
    for (int cl = 0; cl < 16; ++cl) {
        const int ci = cib + cl;
        const float* xc = x + ci * P;
        float v[9];
        #pragma unroll
        for (int kh = 0; kh < 3; ++kh) {
            int hh = h + kh - 1;
            bool hok = (unsigned)hh < 256u;
            const float* rp = xc + hh * WW;
            v[kh * 3 + 0] = (hok && x0 > 0)   ? rp[x0 - 1] : 0.f;
            v[kh * 3 + 1] = hok               ? rp[x0]     : 0.f;
            v[kh * 3 + 2] = (hok && x0 < 255) ? rp[x0 + 1] : 0.f;
        }
        cs[pxg][ci] = v[4];
        const float* wp = aue_wt + ci * 36;   // [k9][co4], uniform -> s_load
        #pragma unroll
        for (int k = 0; k < 9; ++k) {
            float vv = v[k];
            #pragma unroll
            for (int co = 0; co < 4; ++co)
                pa[co] = fmaf(vv, wp[k * 4 + co], pa[co]);
        }
    }
    #pragma unroll
    for (int co = 0; co < 4; ++co) pr[co][g][pxg] = pa[co];
    __syncthreads();

    {
        float s = aue_b[g] + pr[g][0][pxg] + pr[g][1][pxg]
                           + pr[g][2][pxg] + pr[g][3][pxg];
        AU[g * P + p] = fast_sigmoid(s);
    }

    float xv[64];
    #pragma unroll
    for (int c = 0; c < 64; ++c) xv[c] = cs[pxg][c];
    float msv = msin[g * P + p];
    float bo  = b4[g];
    float vals[10];
    float s = 0.f;
    #pragma unroll
    for (int t = 0; t < 10; ++t) {
        float a = bo;
        const float* mwp = mw + t * 256 + g * 64;   // uniform -> s_load
        #pragma unroll
        for (int c = 0; c < 64; ++c) a = fmaf(mwp[c], xv[c], a);
        float v = fast_tanh(a) + msv;
        vals[t] = v;
        s += v;
    }
    float m = s * 0.1f;
    MEAN[g * P + p] = m;
    float var = 0.f;
    #pragma unroll
    for (int t = 0; t < 10; ++t) { float d = vals[t] - m; var = fmaf(d, d, var); }
    EU[g * P + p] = var * (1.0f / 9.0f);
}

// ---------------------------------------------------------------------------
// Fused spatial-gate chain (scalar weights, no LDS).
__global__ __launch_bounds__(256) void spa_fused_k(
        const float* __restrict__ U,
        const float* __restrict__ w0, const float* __restrict__ b0,
        const float* __restrict__ w1, const float* __restrict__ b1,
        const float* __restrict__ w2, const float* __restrict__ b2,
        float* __restrict__ spat, int flip) {
    int p = blockIdx.x * 256 + threadIdx.x;
    int h = p >> 8, x0 = p & 255;
    float u[4][9];
    #pragma unroll
    for (int ci = 0; ci < 4; ++ci) {
        const float* up = U + ci * P;
        #pragma unroll
        for (int kh = 0; kh < 3; ++kh) {
            int hh = h + kh - 1;
            bool hok = (unsigned)hh < 256u;
            #pragma unroll
            for (int kw = 0; kw < 3; ++kw) {
                int wx = x0 + kw - 1;
                bool ok = hok && (unsigned)wx < 256u;
                float v = ok ? up[hh * WW + wx] : 0.f;
                if (flip && ok) v = 1.f - v;
                u[ci][kh * 3 + kw] = v;
            }
        }
    }
    float a1[9];
    #pragma unroll
    for (int co = 0; co < 9; ++co) {
        float s = b0[co];
        #pragma unroll
        for (int ci = 0; ci < 4; ++ci)
            #pragma unroll
            for (int k = 0; k < 9; ++k)
                s = fmaf(u[ci][k], w0[co * 36 + ci * 9 + k], s);
        a1[co] = fmaxf(s, 0.f);
    }
    float a2[9];
    #pragma unroll
    for (int co = 0; co < 9; ++co) {
        float s = b1[co];
        #pragma unroll
        for (int ci = 0; ci < 9; ++ci) s = fmaf(a1[ci], w1[co * 9 + ci], s);
        a2[co] = fmaxf(s, 0.f);
    }
    #pragma unroll
    for (int co = 0; co < 9; ++co) {
        float s = b2[co];
        #pragma unroll
        for (int ci = 0; ci < 9; ++ci) s = fmaf(a2[ci], w2[co * 9 + ci], s);
        spat[co * P + p] = fast_sigmoid(s);
    }
}

// ---------------------------------------------------------------------------
// Spectral-gate MLP v2: block = 64 px x 4 wave-groups; h2 shared via LDS.
__global__ __launch_bounds__(256) void spe2_k(
        const float* __restrict__ U, int flip,
        const float* __restrict__ w0, const float* __restrict__ b0,
        const float* __restrict__ w1t, const float* __restrict__ b1,
        const float* __restrict__ w2t, const float* __restrict__ b2,
        float* __restrict__ spec) {
    __shared__ float h2s[64 * 64];   // [ci][px] 16 KB
    const int tid = threadIdx.x;
    const int pxg = tid & 63;
    const int g   = __builtin_amdgcn_readfirstlane(tid >> 6);  // wave index
    const int cb  = g * 16;
    const int p   = blockIdx.x * 64 + pxg;

    float u[4];
    #pragma unroll
    for (int ci = 0; ci < 4; ++ci) {
        float v = U[ci * P + p];
        u[ci] = flip ? 1.f - v : v;
    }
    float h2[16];
    #pragma unroll
    for (int j = 0; j < 16; ++j) h2[j] = b1[cb + j];
    #pragma unroll 8
    for (int ci = 0; ci < 64; ++ci) {
        float s = b0[ci];
        #pragma unroll
        for (int k = 0; k < 4; ++k) s = fmaf(u[k], w0[ci * 4 + k], s);
        float hv = fmaxf(s, 0.f);
        const float* wr = w1t + ci * 64 + cb;      // uniform -> s_load
        #pragma unroll
        for (int j = 0; j < 16; ++j) h2[j] = fmaf(hv, wr[j], h2[j]);
    }
    #pragma unroll
    for (int j = 0; j < 16; ++j)
        h2s[(cb + j) * 64 + pxg] = fmaxf(h2[j], 0.f);
    __syncthreads();

    float h3[16];
    #pragma unroll
    for (int j = 0; j < 16; ++j) h3[j] = b2[cb + j];
    #pragma unroll 8
    for (int ci = 0; ci < 64; ++ci) {
        float hv = h2s[ci * 64 + pxg];
        const float* wr = w2t + ci * 64 + cb;      // uniform -> s_load
        #pragma unroll
        for (int j = 0; j < 16; ++j) h3[j] = fmaf(hv, wr[j], h3[j]);
    }
    #pragma unroll
    for (int j = 0; j < 16; ++j)
        spec[(cb + j) * P + p] = fast_sigmoid(h3[j]);
}

// ---------------------------------------------------------------------------
// uaconv v4: 256 threads = 64 px x 4 n-groups; scalar weights [n][k][m];
// LDS cross-group reduction (8 KB); fused 1x1 conv (cwt [m][mo]) + lrelu.
__global__ __launch_bounds__(256) void uaconv4_k(
        const float* __restrict__ xa, const float* __restrict__ xb,
        const float* __restrict__ spec, const float* __restrict__ spat,
        const float* __restrict__ wt, const float* __restrict__ cwt,
        const float* __restrict__ cb, float* __restrict__ fout) {
    __shared__ float red[8 * 4 * 64];   // [m-oct][g][px]  8 KB
    const int tid = threadIdx.x;
    const int pxl = tid & 63;
    const int g   = __builtin_amdgcn_readfirstlane(tid >> 6);  // wave-uniform
    const int p   = blockIdx.x * 64 + pxl;
    const int h = p >> 8, x0 = p & 255;
    const float* xbase = (g < 2) ? (xa + g * 16 * P) : (xb + (g - 2) * 16 * P);
    const int nbase = g * 16;

    float sv[9];
    #pragma unroll
    for (int k = 0; k < 9; ++k) sv[k] = spat[k * P + p];
    float acc[32];
    #pragma unroll
    for (int m = 0; m < 32; ++m) acc[m] = 0.f;

    for (int nl = 0; nl < 16; ++nl) {
        const float* xc = xbase + nl * P;
        float s = spec[(nbase + nl) * P + p];
        float q[9];
        #pragma unroll
        for (int kh = 0; kh < 3; ++kh) {
            int hh = h + kh - 1;
            bool hok = (unsigned)hh < 256u;
            #pragma unroll
            for (int kw = 0; kw < 3; ++kw) {
                int wx = x0 + kw - 1;
                float v = (hok && (unsigned)wx < 256u) ? xc[hh * WW + wx] : 0.f;
                q[kh * 3 + kw] = v * s * sv[kh * 3 + kw];
            }
        }
        const float* wn = wt + (nbase + nl) * 288;
        #pragma unroll
        for (int k = 0; k < 9; ++k) {
            float qk = q[k];
            const float* wp = wn + k * 32;
            #pragma unroll
            for (int m = 0; m < 32; ++m)
                acc[m] = fmaf(qk, wp[m], acc[m]);   // s-operand FMA
        }
    }

    float fo[8];
    #pragma unroll
    for (int jo = 0; jo < 8; ++jo) fo[jo] = cb[g * 8 + jo];
    #pragma unroll
    for (int r = 0; r < 4; ++r) {
        if (r) __syncthreads();
        #pragma unroll
        for (int j = 0; j < 8; ++j)
            red[(j * 4 + g) * 64 + pxl] = acc[r * 8 + j];
        __syncthreads();
        #pragma unroll
        for (int j = 0; j < 8; ++j) {
            int m = r * 8 + j;
            float y = red[(j * 4 + 0) * 64 + pxl] + red[(j * 4 + 1) * 64 + pxl]
                    + red[(j * 4 + 2) * 64 + pxl] + red[(j * 4 + 3) * 64 + pxl];
            const float* cwp = cwt + m * 32 + g * 8;
            #pragma unroll
            for (int jo = 0; jo < 8; ++jo)
                fo[jo] = fmaf(y, cwp[jo], fo[jo]);
        }
    }
    #pragma unroll
    for (int jo = 0; jo < 8; ++jo) {
        float v = fo[jo];
        fout[(g * 8 + jo) * P + p] = v > 0.f ? v : 0.2f * v;
    }
}

// ---------------------------------------------------------------------------
extern "C" void kernel_launch(void* const* d_in, const int* in_sizes, int n_in,
                              void* d_out, int out_size, void* d_ws, size_t ws_size,
                              hipStream_t stream) {
    const float* F1        = (const float*)d_in[0];
    const float* ms        = (const float*)d_in[1];
    const float* pan       = (const float*)d_in[2];
    const float* masks_u   = (const float*)d_in[3];
    const float* ue_conv_w = (const float*)d_in[4];
    const float* ue_conv_b = (const float*)d_in[5];
    const float* ue_out_w  = (const float*)d_in[6];
    const float* ue_out_b  = (const float*)d_in[7];
    const float* ue_aue_w  = (const float*)d_in[8];
    const float* ue_aue_b  = (const float*)d_in[9];
    const float* conv1_w   = (const float*)d_in[10];
    const float* conv1_b   = (const float*)d_in[11];
    const float* conv2_w   = (const float*)d_in[12];
    const float* conv2_b   = (const float*)d_in[13];
    const float* spa1_w0 = (const float*)d_in[14];
    const float* spa1_b0 = (const float*)d_in[15];
    const float* spa1_w1 = (const float*)d_in[16];
    const float* spa1_b1 = (const float*)d_in[17];
    const float* spa1_w2 = (const float*)d_in[18];
    const float* spa1_b2 = (const float*)d_in[19];
    const float* spe1_w0 = (const float*)d_in[20];
    const float* spe1_b0 = (const float*)d_in[21];
    const float* spe1_w1 = (const float*)d_in[22];
    const float* spe1_b1 = (const float*)d_in[23];
    const float* spe1_w2 = (const float*)d_in[24];
    const float* spe1_b2 = (const float*)d_in[25];
    const float* ua1_w   = (const float*)d_in[26];
    const float* spa2_w0 = (const float*)d_in[27];
    const float* spa2_b0 = (const float*)d_in[28];
    const float* spa2_w1 = (const float*)d_in[29];
    const float* spa2_b1 = (const float*)d_in[30];
    const float* spa2_w2 = (const float*)d_in[31];
    const float* spa2_b2 = (const float*)d_in[32];
    const float* spe2_w0 = (const float*)d_in[33];
    const float* spe2_b0 = (const float*)d_in[34];
    const float* spe2_w1 = (const float*)d_in[35];
    const float* spe2_b1 = (const float*)d_in[36];
    const float* spe2_w2 = (const float*)d_in[37];
    const float* spe2_b2 = (const float*)d_in[38];
    const float* ua2_w   = (const float*)d_in[39];

    float* out  = (float*)d_out;
    float* AU   = out;             // 4*P
    float* EU   = out + 4 * P;     // 4*P
    float* MEAN = out + 8 * P;     // 4*P
    float* FOUT = out + 12 * P;    // 32*P

    float* ws   = (float*)d_ws;
    float* x    = ws;              // 64P
    float* spec = ws + 64 * P;     // 64P
    float* spat = ws + 128 * P;    // 9P
    float* f2   = ws + 137 * P;    // 32P
    float* W    = ws + 169 * P;    // transposed weights + tables
    float* aue_wt = W + 18432;
    float* wt1    = W + 20736;
    float* wt2    = W + 39168;
    float* s1w1t  = W + 57600;
    float* s1w2t  = W + 61696;
    float* s2w1t  = W + 65792;
    float* s2w2t  = W + 69888;
    float* cw1t   = W + 73984;
    float* cw2t   = W + 75008;
    float* mw     = W + 76032;
    ushort* wbfu  = (ushort*)(W + 78592);   // 18432 bf16
    ushort* xbf   = (ushort*)(W + 87808);   // 32*P bf16 NHWC

    dim3 blk(256);

    tobf_k<<<dim3(256), blk, 0, stream>>>(F1, xbf);
    prep_k<<<dim3(380), blk, 0, stream>>>(ue_conv_w, ue_aue_w, ua1_w, ua2_w,
                                          spe1_w1, spe1_w2, spe2_w1, spe2_w2,
                                          conv1_w, conv2_w, masks_u, ue_out_w, W, wbfu);

    // x = conv3x3(F_1; 32->64) via MFMA implicit GEMM
    conv_ue_mfma<<<dim3(1024), blk, 0, stream>>>(xbf, wbfu, ue_conv_b, x);
    // Fused head: AU + EU + MEAN
    head_k<<<dim3(1024), blk, 0, stream>>>(x, aue_wt, ue_aue_b, mw, ue_out_b, ms,
                                           AU, EU, MEAN);

    // ---- uaconv 1 (U = EU, inputs F1 || pan), fused conv1 -> f2 ----
    spa_fused_k<<<dim3(256), blk, 0, stream>>>(EU, spa1_w0, spa1_b0, spa1_w1, spa1_b1,
                                               spa1_w2, spa1_b2, spat, 0);
    spe2_k<<<dim3(1024), blk, 0, stream>>>(EU, 0, spe1_w0, spe1_b0, s1w1t, spe1_b1,
                                           s1w2t, spe1_b2, spec);
    uaconv4_k<<<dim3(1024), blk, 0, stream>>>(F1, pan, spec, spat, wt1, cw1t, conv1_b, f2);

    // ---- uaconv 2 (U = 1-EU, inputs F1 || F_2), fused conv2 -> FOUT ----
    spa_fused_k<<<dim3(256), blk, 0, stream>>>(EU, spa2_w0, spa2_b0, spa2_w1, spa2_b1,
                                               spa2_w2, spa2_b2, spat, 1);
    spe2_k<<<dim3(1024), blk, 0, stream>>>(EU, 1, spe2_w0, spe2_b0, s2w1t, spe2_b1,
                                           s2w2t, spe2_b2, spec);
    uaconv4_k<<<dim3(1024), blk, 0, stream>>>(F1, f2, spec, spat, wt2, cw2t, conv2_b, FOUT);
}

// Round 7
// 171.925 us; speedup vs baseline: 2.5896x; 1.1268x over previous
//
#include <hip/hip_runtime.h>
#include <hip/hip_bf16.h>
#include <math.h>
#include <string.h>

#define P 65536   // H*W
#define HH 256
#define WW 256

typedef __attribute__((ext_vector_type(8))) short bf16x8;
typedef __attribute__((ext_vector_type(4))) float f32x4;

__device__ __forceinline__ float fast_sigmoid(float v) {
    return 1.f / (1.f + __expf(-v));
}
__device__ __forceinline__ float fast_tanh(float a) {
    a = fminf(fmaxf(a, -10.f), 10.f);
    float t = __expf(2.f * a);
    return (t - 1.f) / (t + 1.f);
}
__device__ __forceinline__ ushort f2bf(float f) {
    unsigned u = __float_as_uint(f);
    unsigned r = (u + 0x7fffu + ((u >> 16) & 1u)) >> 16;
    return (ushort)r;
}
__device__ __forceinline__ unsigned pack_bf2(float a, float b) {
    __hip_bfloat162 h = __float22bfloat162_rn(make_float2(a, b));
    unsigned u;
    memcpy(&u, &h, 4);
    return u;
}

// ---------------------------------------------------------------------------
// Weight-prep. Float region W (21248):
//   [0,2304)       aue_wt  [ci64][k9][co4]
//   [2304,6400)    s1w1t   [ci64][co64]
//   [6400,10496)   s1w2t   [ci64][co64]
//   [10496,14592)  s2w1t   [ci64][co64]
//   [14592,18688)  s2w2t   [ci64][co64]
//   [18688,21248)  mw      [t10][o4][c64]
// ushort region wub (55296):
//   [0,18432)      wbfu    [ct4][kp9][n16][ci32]  (ue conv B frags)
//   [18432,36864)  w2bf1   [mo32][K576] K=k*64+n  (cw1 @ ua1, bf16)
//   [36864,55296)  w2bf2   [mo32][K576]           (cw2 @ ua2, bf16)
__global__ void prep_k(const float* __restrict__ ue_w, const float* __restrict__ aue_w,
                       const float* __restrict__ ua1, const float* __restrict__ ua2,
                       const float* __restrict__ s1w1, const float* __restrict__ s1w2,
                       const float* __restrict__ s2w1, const float* __restrict__ s2w2,
                       const float* __restrict__ cw1, const float* __restrict__ cw2,
                       const float* __restrict__ masks_u, const float* __restrict__ w4,
                       float* __restrict__ W, ushort* __restrict__ wub) {
    int i = blockIdx.x * 256 + threadIdx.x;
    if (i < 2304) {                        // aue_w (co4, ci64, 9) -> [ci][k][co]
        int ci = i / 36, r = i % 36, k = r >> 2, co = r & 3;
        W[i] = aue_w[co * 576 + ci * 9 + k];
    } else if (i < 6400) {
        int j = i - 2304;  W[i] = s1w1[(j & 63) * 64 + (j >> 6)];
    } else if (i < 10496) {
        int j = i - 6400;  W[i] = s1w2[(j & 63) * 64 + (j >> 6)];
    } else if (i < 14592) {
        int j = i - 10496; W[i] = s2w1[(j & 63) * 64 + (j >> 6)];
    } else if (i < 18688) {
        int j = i - 14592; W[i] = s2w2[(j & 63) * 64 + (j >> 6)];
    } else if (i < 21248) {                // mw[t][o][c]
        int j = i - 18688;
        int t = j >> 8, o = (j >> 6) & 3, c = j & 63;
        W[i] = (masks_u[t * 64 + c] < 0.8f) ? w4[o * 64 + c] : 0.f;
    } else if (i < 39680) {                // wbfu
        int j = i - 21248;
        int ct = j / 4608, r1 = j % 4608;
        int kp = r1 / 512, r2 = r1 % 512;
        int n = r2 >> 5, ci = r2 & 31;
        wub[j] = f2bf(ue_w[(ct * 16 + n) * 288 + ci * 9 + kp]);
    } else if (i < 58112) {                // w2bf1 = cw1 @ ua1
        int j = i - 39680;
        int mo = j / 576, K = j % 576, k = K >> 6, n = K & 63;
        float s = 0.f;
        for (int m = 0; m < 32; ++m)
            s += cw1[mo * 32 + m] * ua1[m * 576 + n * 9 + k];
        wub[18432 + j] = f2bf(s);
    } else if (i < 76544) {                // w2bf2 = cw2 @ ua2
        int j = i - 58112;
        int mo = j / 576, K = j % 576, k = K >> 6, n = K & 63;
        float s = 0.f;
        for (int m = 0; m < 32; ++m)
            s += cw2[mo * 32 + m] * ua2[m * 576 + n * 9 + k];
        wub[36864 + j] = f2bf(s);
    }
}

// ---------------------------------------------------------------------------
// NCHW f32 (32 ch) -> NHWC bf16
__global__ __launch_bounds__(256) void tobf_k(const float* __restrict__ src,
                                              ushort* __restrict__ dst) {
    int p = blockIdx.x * 256 + threadIdx.x;
    unsigned pk[16];
    #pragma unroll
    for (int c = 0; c < 16; ++c) {
        float a = src[(2 * c) * P + p];
        float b = src[(2 * c + 1) * P + p];
        pk[c] = (unsigned)f2bf(a) | ((unsigned)f2bf(b) << 16);
    }
    uint4* d4 = (uint4*)(dst + (size_t)p * 32);
    #pragma unroll
    for (int q = 0; q < 4; ++q)
        d4[q] = make_uint4(pk[4 * q], pk[4 * q + 1], pk[4 * q + 2], pk[4 * q + 3]);
}

// ---------------------------------------------------------------------------
// ue conv (32->64, 3x3, pad=1) as MFMA implicit GEMM (unchanged from R6).
__global__ __launch_bounds__(256) void conv_ue_mfma(
        const ushort* __restrict__ xbf, const ushort* __restrict__ wbfu,
        const float* __restrict__ bias, float* __restrict__ out) {
    __shared__ float tls[4][272];
    const int tid  = threadIdx.x;
    const int lane = tid & 63;
    const int wv   = __builtin_amdgcn_readfirstlane(tid >> 6);
    const int lrow = lane & 15;
    const int kg   = lane >> 4;

    bf16x8 zf;
    #pragma unroll
    for (int z = 0; z < 8; ++z) zf[z] = 0;

    bf16x8 Bf[9];
    const ushort* wb = wbfu + wv * 4608;
    #pragma unroll
    for (int kp = 0; kp < 9; ++kp)
        Bf[kp] = *(const bf16x8*)(wb + kp * 512 + lrow * 32 + kg * 8);

    const float bco = bias[wv * 16 + lrow];
    float* tw = tls[wv];

    for (int si = 0; si < 4; ++si) {
        const int s   = blockIdx.x * 4 + si;
        const int row = s >> 4;
        const int cb  = (s & 15) << 4;
        const int pb  = s << 4;
        f32x4 acc = {bco, bco, bco, bco};
        #pragma unroll
        for (int dh = -1; dh <= 1; ++dh) {
            if ((unsigned)(row + dh) >= 256u) continue;
            #pragma unroll
            for (int dw = -1; dw <= 1; ++dw) {
                const bool kill = (dw == -1 && cb == 0 && lrow == 0) ||
                                  (dw == 1 && cb == 240 && lrow == 15);
                const int apx = kill ? pb : (pb + dh * 256 + dw + lrow);
                bf16x8 Af = *(const bf16x8*)(xbf + (size_t)apx * 32 + kg * 8);
                if (kill) Af = zf;
                acc = __builtin_amdgcn_mfma_f32_16x16x32_bf16(
                          Af, Bf[(dh + 1) * 3 + (dw + 1)], acc, 0, 0, 0);
            }
        }
        #pragma unroll
        for (int j = 0; j < 4; ++j)
            tw[(kg * 4 + j) * 17 + lrow] = acc[j];
        asm volatile("s_waitcnt lgkmcnt(0)" ::: "memory");
        #pragma unroll
        for (int it = 0; it < 4; ++it) {
            const int co = kg + it * 4;
            out[(wv * 16 + co) * P + pb + lrow] = tw[lrow * 17 + co];
        }
        asm volatile("s_waitcnt lgkmcnt(0)" ::: "memory");
    }
}

// ---------------------------------------------------------------------------
// Fused head: AU = sigmoid(conv3x3(x;64->4)), EU/MEAN = var/mean of xs.
__global__ __launch_bounds__(256) void head_k(
        const float* __restrict__ x, const float* __restrict__ aue_wt,
        const float* __restrict__ aue_b, const float* __restrict__ mw,
        const float* __restrict__ b4, const float* __restrict__ msin,
        float* __restrict__ AU, float* __restrict__ EU, float* __restrict__ MEAN) {
    __shared__ float cs[64][65];
    __shared__ float pr[4][4][64];
    const int tid = threadIdx.x;
    const int pxg = tid & 63;
    const int g   = __builtin_amdgcn_readfirstlane(tid >> 6);
    const int p   = blockIdx.x * 64 + pxg;
    const int h = p >> 8, x0 = p & 255;
    const int cib = g * 16;

    float pa[4] = {0.f, 0.f, 0.f, 0.f};
    #pragma unroll 4
    for (int cl = 0; cl < 16; ++cl) {
        const int ci = cib + cl;
        const float* xc = x + ci * P;
        float v[9];
        #pragma unroll
        for (int kh = 0; kh < 3; ++kh) {
            int hh = h + kh - 1;
            bool hok = (unsigned)hh < 256u;
            const float* rp = xc + hh * WW;
            v[kh * 3 + 0] = (hok && x0 > 0)   ? rp[x0 - 1] : 0.f;
            v[kh * 3 + 1] = hok               ? rp[x0]     : 0.f;
            v[kh * 3 + 2] = (hok && x0 < 255) ? rp[x0 + 1] : 0.f;
        }
        cs[pxg][ci] = v[4];
        const float* wp = aue_wt + ci * 36;
        #pragma unroll
        for (int k = 0; k < 9; ++k) {
            float vv = v[k];
            #pragma unroll
            for (int co = 0; co < 4; ++co)
                pa[co] = fmaf(vv, wp[k * 4 + co], pa[co]);
        }
    }
    #pragma unroll
    for (int co = 0; co < 4; ++co) pr[co][g][pxg] = pa[co];
    __syncthreads();

    {
        float s = aue_b[g] + pr[g][0][pxg] + pr[g][1][pxg]
                           + pr[g][2][pxg] + pr[g][3][pxg];
        AU[g * P + p] = fast_sigmoid(s);
    }

    float xv[64];
    #pragma unroll
    for (int c = 0; c < 64; ++c) xv[c] = cs[pxg][c];
    float msv = msin[g * P + p];
    float bo  = b4[g];
    float vals[10];
    float s = 0.f;
    #pragma unroll
    for (int t = 0; t < 10; ++t) {
        float a = bo;
        const float* mwp = mw + t * 256 + g * 64;
        #pragma unroll
        for (int c = 0; c < 64; ++c) a = fmaf(mwp[c], xv[c], a);
        float v = fast_tanh(a) + msv;
        vals[t] = v;
        s += v;
    }
    float m = s * 0.1f;
    MEAN[g * P + p] = m;
    float var = 0.f;
    #pragma unroll
    for (int t = 0; t < 10; ++t) { float d = vals[t] - m; var = fmaf(d, d, var); }
    EU[g * P + p] = var * (1.0f / 9.0f);
}

// ---------------------------------------------------------------------------
// Fused spatial-gate chain (scalar weights, no LDS).
__global__ __launch_bounds__(256) void spa_fused_k(
        const float* __restrict__ U,
        const float* __restrict__ w0, const float* __restrict__ b0,
        const float* __restrict__ w1, const float* __restrict__ b1,
        const float* __restrict__ w2, const float* __restrict__ b2,
        float* __restrict__ spat, int flip) {
    int p = blockIdx.x * 256 + threadIdx.x;
    int h = p >> 8, x0 = p & 255;
    float u[4][9];
    #pragma unroll
    for (int ci = 0; ci < 4; ++ci) {
        const float* up = U + ci * P;
        #pragma unroll
        for (int kh = 0; kh < 3; ++kh) {
            int hh = h + kh - 1;
            bool hok = (unsigned)hh < 256u;
            #pragma unroll
            for (int kw = 0; kw < 3; ++kw) {
                int wx = x0 + kw - 1;
                bool ok = hok && (unsigned)wx < 256u;
                float v = ok ? up[hh * WW + wx] : 0.f;
                if (flip && ok) v = 1.f - v;
                u[ci][kh * 3 + kw] = v;
            }
        }
    }
    float a1[9];
    #pragma unroll
    for (int co = 0; co < 9; ++co) {
        float s = b0[co];
        #pragma unroll
        for (int ci = 0; ci < 4; ++ci)
            #pragma unroll
            for (int k = 0; k < 9; ++k)
                s = fmaf(u[ci][k], w0[co * 36 + ci * 9 + k], s);
        a1[co] = fmaxf(s, 0.f);
    }
    float a2[9];
    #pragma unroll
    for (int co = 0; co < 9; ++co) {
        float s = b1[co];
        #pragma unroll
        for (int ci = 0; ci < 9; ++ci) s = fmaf(a1[ci], w1[co * 9 + ci], s);
        a2[co] = fmaxf(s, 0.f);
    }
    #pragma unroll
    for (int co = 0; co < 9; ++co) {
        float s = b2[co];
        #pragma unroll
        for (int ci = 0; ci < 9; ++ci) s = fmaf(a2[ci], w2[co * 9 + ci], s);
        spat[co * P + p] = fast_sigmoid(s);
    }
}

// ---------------------------------------------------------------------------
// Spectral-gate MLP: block = 64 px x 4 wave-groups; NHWC f32 output.
__global__ __launch_bounds__(256) void spe2_k(
        const float* __restrict__ U, int flip,
        const float* __restrict__ w0, const float* __restrict__ b0,
        const float* __restrict__ w1t, const float* __restrict__ b1,
        const float* __restrict__ w2t, const float* __restrict__ b2,
        float* __restrict__ specn) {
    __shared__ float h2s[64 * 64];
    const int tid = threadIdx.x;
    const int pxg = tid & 63;
    const int g   = __builtin_amdgcn_readfirstlane(tid >> 6);
    const int cb  = g * 16;
    const int p   = blockIdx.x * 64 + pxg;

    float u[4];
    #pragma unroll
    for (int ci = 0; ci < 4; ++ci) {
        float v = U[ci * P + p];
        u[ci] = flip ? 1.f - v : v;
    }
    float h2[16];
    #pragma unroll
    for (int j = 0; j < 16; ++j) h2[j] = b1[cb + j];
    #pragma unroll 8
    for (int ci = 0; ci < 64; ++ci) {
        float s = b0[ci];
        #pragma unroll
        for (int k = 0; k < 4; ++k) s = fmaf(u[k], w0[ci * 4 + k], s);
        float hv = fmaxf(s, 0.f);
        const float* wr = w1t + ci * 64 + cb;
        #pragma unroll
        for (int j = 0; j < 16; ++j) h2[j] = fmaf(hv, wr[j], h2[j]);
    }
    #pragma unroll
    for (int j = 0; j < 16; ++j)
        h2s[(cb + j) * 64 + pxg] = fmaxf(h2[j], 0.f);
    __syncthreads();

    float h3[16];
    #pragma unroll
    for (int j = 0; j < 16; ++j) h3[j] = b2[cb + j];
    #pragma unroll 8
    for (int ci = 0; ci < 64; ++ci) {
        float hv = h2s[ci * 64 + pxg];
        const float* wr = w2t + ci * 64 + cb;
        #pragma unroll
        for (int j = 0; j < 16; ++j) h3[j] = fmaf(hv, wr[j], h3[j]);
    }
    float* dst = specn + (size_t)p * 64 + cb;
    #pragma unroll
    for (int q = 0; q < 4; ++q)
        *(float4*)(dst + 4 * q) = make_float4(fast_sigmoid(h3[4 * q]),
                                              fast_sigmoid(h3[4 * q + 1]),
                                              fast_sigmoid(h3[4 * q + 2]),
                                              fast_sigmoid(h3[4 * q + 3]));
}

// ---------------------------------------------------------------------------
// uaconv v5: MFMA implicit GEMM, 1x1 conv folded into W2 = cw @ Wr.
// Wave = one 16-px strip; A = gated patches (built on the fly, bf16),
// B = w2bf [mo32][K576] K-major (K = k*64 + n); 18 K-chunks x 2 mo-tiles.
// OUTMODE 0: f2 NHWC bf16; OUTMODE 1: FOUT f32 CHW. Both +cb, lrelu.
template<int OUTMODE>
__global__ __launch_bounds__(256) void uaconv5_k(
        const ushort* __restrict__ xa, const ushort* __restrict__ xb,
        const float* __restrict__ specn, const float* __restrict__ spat,
        const ushort* __restrict__ w2bf, const float* __restrict__ cb,
        float* __restrict__ outf, ushort* __restrict__ outh) {
    __shared__ float tls[4][16 * 35];
    const int tid  = threadIdx.x;
    const int lane = tid & 63;
    const int wv   = __builtin_amdgcn_readfirstlane(tid >> 6);
    const int lrow = lane & 15;
    const int kg   = lane >> 4;
    const int s    = blockIdx.x * 4 + wv;
    const int row  = s >> 4;
    const int c16  = s & 15;
    const int pb   = s << 4;
    const int px   = pb + lrow;

    // spec for this lane's two n-windows (8 f32 each)
    float sl[8], sh[8];
    {
        const float* sp = specn + (size_t)px * 64 + kg * 8;
        float4 a = *(const float4*)sp;
        float4 b = *(const float4*)(sp + 4);
        sl[0] = a.x; sl[1] = a.y; sl[2] = a.z; sl[3] = a.w;
        sl[4] = b.x; sl[5] = b.y; sl[6] = b.z; sl[7] = b.w;
        float4 c = *(const float4*)(sp + 32);
        float4 d = *(const float4*)(sp + 36);
        sh[0] = c.x; sh[1] = c.y; sh[2] = c.z; sh[3] = c.w;
        sh[4] = d.x; sh[5] = d.y; sh[6] = d.z; sh[7] = d.w;
    }
    const ushort* b0p = w2bf + lrow * 576 + kg * 8;
    const ushort* b1p = w2bf + (16 + lrow) * 576 + kg * 8;

    f32x4 acc0 = {0.f, 0.f, 0.f, 0.f};
    f32x4 acc1 = {0.f, 0.f, 0.f, 0.f};

    #pragma unroll
    for (int k = 0; k < 9; ++k) {
        const int dh = k / 3 - 1, dw = k % 3 - 1;
        if ((unsigned)(row + dh) >= 256u) continue;   // wave-uniform skip
        const bool kill = (dw == -1 && c16 == 0 && lrow == 0) ||
                          (dw == 1 && c16 == 15 && lrow == 15);
        float stk = spat[k * P + px];
        if (kill) stk = 0.f;
        const int pxe = kill ? px : (px + dh * 256 + dw);
        #pragma unroll
        for (int par = 0; par < 2; ++par) {
            const ushort* src = (par == 0) ? (xa + (size_t)pxe * 32 + kg * 8)
                                           : (xb + (size_t)pxe * 32 + kg * 8);
            uint4 raw = *(const uint4*)src;
            const float* ss = par ? sh : sl;
            unsigned rr[4] = {raw.x, raw.y, raw.z, raw.w};
            union { unsigned u[4]; bf16x8 v; } af;
            #pragma unroll
            for (int q = 0; q < 4; ++q) {
                float e0 = __uint_as_float(rr[q] << 16)          * (ss[2 * q] * stk);
                float e1 = __uint_as_float(rr[q] & 0xffff0000u)  * (ss[2 * q + 1] * stk);
                af.u[q] = pack_bf2(e0, e1);
            }
            const int ki = k * 2 + par;
            bf16x8 bf0 = *(const bf16x8*)(b0p + ki * 32);
            bf16x8 bf1 = *(const bf16x8*)(b1p + ki * 32);
            acc0 = __builtin_amdgcn_mfma_f32_16x16x32_bf16(af.v, bf0, acc0, 0, 0, 0);
            acc1 = __builtin_amdgcn_mfma_f32_16x16x32_bf16(af.v, bf1, acc1, 0, 0, 0);
        }
    }

    // epilogue: +bias, lrelu, transpose via per-wave LDS tile [16px][35]
    const float cb0 = cb[lrow], cb1 = cb[16 + lrow];
    float* tw = tls[wv];
    #pragma unroll
    for (int j = 0; j < 4; ++j) {
        float y0 = acc0[j] + cb0; y0 = y0 > 0.f ? y0 : 0.2f * y0;
        float y1 = acc1[j] + cb1; y1 = y1 > 0.f ? y1 : 0.2f * y1;
        tw[(kg * 4 + j) * 35 + lrow] = y0;
        tw[(kg * 4 + j) * 35 + 16 + lrow] = y1;
    }
    asm volatile("s_waitcnt lgkmcnt(0)" ::: "memory");
    if constexpr (OUTMODE == 0) {
        const float* rp = tw + lrow * 35 + kg * 8;
        unsigned o[4];
        #pragma unroll
        for (int q = 0; q < 4; ++q)
            o[q] = pack_bf2(rp[2 * q], rp[2 * q + 1]);
        *(uint4*)(outh + (size_t)(pb + lrow) * 32 + kg * 8) =
            make_uint4(o[0], o[1], o[2], o[3]);
    } else {
        #pragma unroll
        for (int it = 0; it < 8; ++it) {
            const int mo = kg * 8 + it;
            outf[mo * P + pb + lrow] = tw[lrow * 35 + mo];
        }
    }
    asm volatile("s_waitcnt lgkmcnt(0)" ::: "memory");
}

// ---------------------------------------------------------------------------
extern "C" void kernel_launch(void* const* d_in, const int* in_sizes, int n_in,
                              void* d_out, int out_size, void* d_ws, size_t ws_size,
                              hipStream_t stream) {
    const float* F1        = (const float*)d_in[0];
    const float* ms        = (const float*)d_in[1];
    const float* pan       = (const float*)d_in[2];
    const float* masks_u   = (const float*)d_in[3];
    const float* ue_conv_w = (const float*)d_in[4];
    const float* ue_conv_b = (const float*)d_in[5];
    const float* ue_out_w  = (const float*)d_in[6];
    const float* ue_out_b  = (const float*)d_in[7];
    const float* ue_aue_w  = (const float*)d_in[8];
    const float* ue_aue_b  = (const float*)d_in[9];
    const float* conv1_w   = (const float*)d_in[10];
    const float* conv1_b   = (const float*)d_in[11];
    const float* conv2_w   = (const float*)d_in[12];
    const float* conv2_b   = (const float*)d_in[13];
    const float* spa1_w0 = (const float*)d_in[14];
    const float* spa1_b0 = (const float*)d_in[15];
    const float* spa1_w1 = (const float*)d_in[16];
    const float* spa1_b1 = (const float*)d_in[17];
    const float* spa1_w2 = (const float*)d_in[18];
    const float* spa1_b2 = (const float*)d_in[19];
    const float* spe1_w0 = (const float*)d_in[20];
    const float* spe1_b0 = (const float*)d_in[21];
    const float* spe1_w1 = (const float*)d_in[22];
    const float* spe1_b1 = (const float*)d_in[23];
    const float* spe1_w2 = (const float*)d_in[24];
    const float* spe1_b2 = (const float*)d_in[25];
    const float* ua1_w   = (const float*)d_in[26];
    const float* spa2_w0 = (const float*)d_in[27];
    const float* spa2_b0 = (const float*)d_in[28];
    const float* spa2_w1 = (const float*)d_in[29];
    const float* spa2_b1 = (const float*)d_in[30];
    const float* spa2_w2 = (const float*)d_in[31];
    const float* spa2_b2 = (const float*)d_in[32];
    const float* spe2_w0 = (const float*)d_in[33];
    const float* spe2_b0 = (const float*)d_in[34];
    const float* spe2_w1 = (const float*)d_in[35];
    const float* spe2_b1 = (const float*)d_in[36];
    const float* spe2_w2 = (const float*)d_in[37];
    const float* spe2_b2 = (const float*)d_in[38];
    const float* ua2_w   = (const float*)d_in[39];

    float* out  = (float*)d_out;
    float* AU   = out;             // 4*P
    float* EU   = out + 4 * P;     // 4*P
    float* MEAN = out + 8 * P;     // 4*P
    float* FOUT = out + 12 * P;    // 32*P

    float* ws    = (float*)d_ws;
    float* x     = ws;                         // 64P
    float* specn = ws + 64 * P;                // 64P (NHWC)
    float* spat  = ws + 128 * P;               // 9P
    ushort* xbf   = (ushort*)(ws + 137 * P);   // 32P bf16 (16P f32)
    ushort* panbf = (ushort*)(ws + 153 * P);   // 32P bf16
    float* W     = ws + 169 * P;               // 21248 f32
    float* aue_wt = W;
    float* s1w1t  = W + 2304;
    float* s1w2t  = W + 6400;
    float* s2w1t  = W + 10496;
    float* s2w2t  = W + 14592;
    float* mw     = W + 18688;
    ushort* wub   = (ushort*)(W + 21248);      // 55296 ushort (27648 f32)
    ushort* wbfu  = wub;
    ushort* w2bf1 = wub + 18432;
    ushort* w2bf2 = wub + 36864;
    ushort* f2bf  = (ushort*)(W + 21248 + 27648);  // 32P bf16

    dim3 blk(256);

    tobf_k<<<dim3(256), blk, 0, stream>>>(F1, xbf);
    tobf_k<<<dim3(256), blk, 0, stream>>>(pan, panbf);
    prep_k<<<dim3(300), blk, 0, stream>>>(ue_conv_w, ue_aue_w, ua1_w, ua2_w,
                                          spe1_w1, spe1_w2, spe2_w1, spe2_w2,
                                          conv1_w, conv2_w, masks_u, ue_out_w, W, wub);

    // x = conv3x3(F_1; 32->64) via MFMA
    conv_ue_mfma<<<dim3(1024), blk, 0, stream>>>(xbf, wbfu, ue_conv_b, x);
    // Fused head: AU + EU + MEAN
    head_k<<<dim3(1024), blk, 0, stream>>>(x, aue_wt, ue_aue_b, mw, ue_out_b, ms,
                                           AU, EU, MEAN);

    // ---- uaconv 1 (U = EU, inputs F1 || pan) + folded conv1 -> f2 bf16 ----
    spa_fused_k<<<dim3(256), blk, 0, stream>>>(EU, spa1_w0, spa1_b0, spa1_w1, spa1_b1,
                                               spa1_w2, spa1_b2, spat, 0);
    spe2_k<<<dim3(1024), blk, 0, stream>>>(EU, 0, spe1_w0, spe1_b0, s1w1t, spe1_b1,
                                           s1w2t, spe1_b2, specn);
    uaconv5_k<0><<<dim3(1024), blk, 0, stream>>>(xbf, panbf, specn, spat, w2bf1,
                                                 conv1_b, nullptr, f2bf);

    // ---- uaconv 2 (U = 1-EU, inputs F1 || F_2) + folded conv2 -> FOUT ----
    spa_fused_k<<<dim3(256), blk, 0, stream>>>(EU, spa2_w0, spa2_b0, spa2_w1, spa2_b1,
                                               spa2_w2, spa2_b2, spat, 1);
    spe2_k<<<dim3(1024), blk, 0, stream>>>(EU, 1, spe2_w0, spe2_b0, s2w1t, spe2_b1,
                                           s2w2t, spe2_b2, specn);
    uaconv5_k<1><<<dim3(1024), blk, 0, stream>>>(xbf, f2bf, specn, spat, w2bf2,
                                                 conv2_b, FOUT, nullptr);
}

// Round 8
// 157.394 us; speedup vs baseline: 2.8287x; 1.0923x over previous
//
#include <hip/hip_runtime.h>
#include <hip/hip_bf16.h>
#include <math.h>
#include <string.h>

#define P 65536   // H*W
#define HH 256
#define WW 256

typedef __attribute__((ext_vector_type(8))) short bf16x8;
typedef __attribute__((ext_vector_type(4))) float f32x4;

__device__ __forceinline__ float fast_sigmoid(float v) {
    return 1.f / (1.f + __expf(-v));
}
__device__ __forceinline__ float fast_tanh(float a) {
    a = fminf(fmaxf(a, -10.f), 10.f);
    float t = __expf(2.f * a);
    return (t - 1.f) / (t + 1.f);
}
__device__ __forceinline__ ushort f2bf(float f) {
    unsigned u = __float_as_uint(f);
    unsigned r = (u + 0x7fffu + ((u >> 16) & 1u)) >> 16;
    return (ushort)r;
}
__device__ __forceinline__ unsigned pack_bf2(float a, float b) {
    __hip_bfloat162 h = __float22bfloat162_rn(make_float2(a, b));
    unsigned u;
    memcpy(&u, &h, 4);
    return u;
}

// ---------------------------------------------------------------------------
// Weight-prep. Float region W (21248):
//   [0,2304)       aue_wt  [ci64][k9][co4]
//   [2304,6400)    s1w1t   [ci64][co64]
//   [6400,10496)   s1w2t   [ci64][co64]
//   [10496,14592)  s2w1t   [ci64][co64]
//   [14592,18688)  s2w2t   [ci64][co64]
//   [18688,21248)  mw      [t10][o4][c64]
// ushort region wub (55296):
//   [0,18432)      wbfu    [ct4][kp9][n16][ci32]  (ue conv B frags)
//   [18432,36864)  w2bf1   [mo32][K576] K=k*64+n  (cw1 @ ua1, bf16)
//   [36864,55296)  w2bf2   [mo32][K576]           (cw2 @ ua2, bf16)
__global__ void prep_k(const float* __restrict__ ue_w, const float* __restrict__ aue_w,
                       const float* __restrict__ ua1, const float* __restrict__ ua2,
                       const float* __restrict__ s1w1, const float* __restrict__ s1w2,
                       const float* __restrict__ s2w1, const float* __restrict__ s2w2,
                       const float* __restrict__ cw1, const float* __restrict__ cw2,
                       const float* __restrict__ masks_u, const float* __restrict__ w4,
                       float* __restrict__ W, ushort* __restrict__ wub) {
    int i = blockIdx.x * 256 + threadIdx.x;
    if (i < 2304) {                        // aue_w (co4, ci64, 9) -> [ci][k][co]
        int ci = i / 36, r = i % 36, k = r >> 2, co = r & 3;
        W[i] = aue_w[co * 576 + ci * 9 + k];
    } else if (i < 6400) {
        int j = i - 2304;  W[i] = s1w1[(j & 63) * 64 + (j >> 6)];
    } else if (i < 10496) {
        int j = i - 6400;  W[i] = s1w2[(j & 63) * 64 + (j >> 6)];
    } else if (i < 14592) {
        int j = i - 10496; W[i] = s2w1[(j & 63) * 64 + (j >> 6)];
    } else if (i < 18688) {
        int j = i - 14592; W[i] = s2w2[(j & 63) * 64 + (j >> 6)];
    } else if (i < 21248) {                // mw[t][o][c]
        int j = i - 18688;
        int t = j >> 8, o = (j >> 6) & 3, c = j & 63;
        W[i] = (masks_u[t * 64 + c] < 0.8f) ? w4[o * 64 + c] : 0.f;
    } else if (i < 39680) {                // wbfu
        int j = i - 21248;
        int ct = j / 4608, r1 = j % 4608;
        int kp = r1 / 512, r2 = r1 % 512;
        int n = r2 >> 5, ci = r2 & 31;
        wub[j] = f2bf(ue_w[(ct * 16 + n) * 288 + ci * 9 + kp]);
    } else if (i < 58112) {                // w2bf1 = cw1 @ ua1
        int j = i - 39680;
        int mo = j / 576, K = j % 576, k = K >> 6, n = K & 63;
        float s = 0.f;
        for (int m = 0; m < 32; ++m)
            s += cw1[mo * 32 + m] * ua1[m * 576 + n * 9 + k];
        wub[18432 + j] = f2bf(s);
    } else if (i < 76544) {                // w2bf2 = cw2 @ ua2
        int j = i - 58112;
        int mo = j / 576, K = j % 576, k = K >> 6, n = K & 63;
        float s = 0.f;
        for (int m = 0; m < 32; ++m)
            s += cw2[mo * 32 + m] * ua2[m * 576 + n * 9 + k];
        wub[36864 + j] = f2bf(s);
    }
}

// ---------------------------------------------------------------------------
// Both NCHW f32 (32 ch) -> NHWC bf16 tensors in one launch: blocks [0,256) do
// F1 -> xbf, blocks [256,512) do pan -> panbf.
__global__ __launch_bounds__(256) void tobf2_k(const float* __restrict__ F1,
                                               const float* __restrict__ pan,
                                               ushort* __restrict__ xbf,
                                               ushort* __restrict__ panbf) {
    int idx = blockIdx.x * 256 + threadIdx.x;
    const float* src = (idx < P) ? F1 : pan;
    ushort* dst = (idx < P) ? xbf : panbf;
    int p = idx & (P - 1);
    unsigned pk[16];
    #pragma unroll
    for (int c = 0; c < 16; ++c) {
        float a = src[(2 * c) * P + p];
        float b = src[(2 * c + 1) * P + p];
        pk[c] = (unsigned)f2bf(a) | ((unsigned)f2bf(b) << 16);
    }
    uint4* d4 = (uint4*)(dst + (size_t)p * 32);
    #pragma unroll
    for (int q = 0; q < 4; ++q)
        d4[q] = make_uint4(pk[4 * q], pk[4 * q + 1], pk[4 * q + 2], pk[4 * q + 3]);
}

// ---------------------------------------------------------------------------
// ue conv (32->64, 3x3, pad=1) as MFMA implicit GEMM. Output: NHWC bf16
// (xnh[px*64 + co]), each wave writing its 16-co chunk.
__global__ __launch_bounds__(256) void conv_ue_mfma(
        const ushort* __restrict__ xbf, const ushort* __restrict__ wbfu,
        const float* __restrict__ bias, ushort* __restrict__ xnh) {
    __shared__ float tls[4][272];
    const int tid  = threadIdx.x;
    const int lane = tid & 63;
    const int wv   = __builtin_amdgcn_readfirstlane(tid >> 6);
    const int lrow = lane & 15;
    const int kg   = lane >> 4;

    bf16x8 zf;
    #pragma unroll
    for (int z = 0; z < 8; ++z) zf[z] = 0;

    bf16x8 Bf[9];
    const ushort* wb = wbfu + wv * 4608;
    #pragma unroll
    for (int kp = 0; kp < 9; ++kp)
        Bf[kp] = *(const bf16x8*)(wb + kp * 512 + lrow * 32 + kg * 8);

    const float bco = bias[wv * 16 + lrow];
    float* tw = tls[wv];

    for (int si = 0; si < 4; ++si) {
        const int s   = blockIdx.x * 4 + si;
        const int row = s >> 4;
        const int cb  = (s & 15) << 4;
        const int pb  = s << 4;
        f32x4 acc = {bco, bco, bco, bco};
        #pragma unroll
        for (int dh = -1; dh <= 1; ++dh) {
            if ((unsigned)(row + dh) >= 256u) continue;
            #pragma unroll
            for (int dw = -1; dw <= 1; ++dw) {
                const bool kill = (dw == -1 && cb == 0 && lrow == 0) ||
                                  (dw == 1 && cb == 240 && lrow == 15);
                const int apx = kill ? pb : (pb + dh * 256 + dw + lrow);
                bf16x8 Af = *(const bf16x8*)(xbf + (size_t)apx * 32 + kg * 8);
                if (kill) Af = zf;
                acc = __builtin_amdgcn_mfma_f32_16x16x32_bf16(
                          Af, Bf[(dh + 1) * 3 + (dw + 1)], acc, 0, 0, 0);
            }
        }
        // C: col(co)=lrow, rows(px)=kg*4+j -> LDS tile [px][co]
        #pragma unroll
        for (int j = 0; j < 4; ++j)
            tw[(kg * 4 + j) * 17 + lrow] = acc[j];
        asm volatile("s_waitcnt lgkmcnt(0)" ::: "memory");
        {   // row px=lrow: 16 co -> bf16, NHWC chunk store (16B aligned)
            const float* rp = tw + lrow * 17;
            unsigned o[8];
            #pragma unroll
            for (int q = 0; q < 8; ++q)
                o[q] = pack_bf2(rp[2 * q], rp[2 * q + 1]);
            ushort* dst = xnh + (size_t)(pb + lrow) * 64 + wv * 16;
            *(uint4*)dst       = make_uint4(o[0], o[1], o[2], o[3]);
            *(uint4*)(dst + 8) = make_uint4(o[4], o[5], o[6], o[7]);
        }
        asm volatile("s_waitcnt lgkmcnt(0)" ::: "memory");
    }
}

// ---------------------------------------------------------------------------
// Fused head: AU = sigmoid(conv3x3(x;64->4)), EU/MEAN = var/mean of xs.
// x is NHWC bf16. Block = 64 px (one row segment) x 4 wave-groups; group g
// loads ci chunk [16g,16g+16) via 2 x 16B loads per tap.
__global__ __launch_bounds__(256) void head_k(
        const ushort* __restrict__ xnh, const float* __restrict__ aue_wt,
        const float* __restrict__ aue_b, const float* __restrict__ mw,
        const float* __restrict__ b4, const float* __restrict__ msin,
        float* __restrict__ AU, float* __restrict__ EU, float* __restrict__ MEAN) {
    __shared__ float cs[64][65];
    __shared__ float pr[4][4][64];
    const int tid = threadIdx.x;
    const int pxg = tid & 63;
    const int g   = __builtin_amdgcn_readfirstlane(tid >> 6);
    const int p   = blockIdx.x * 64 + pxg;
    const int h = p >> 8, x0 = p & 255;   // h is block-uniform
    const int cib = g * 16;

    float pa[4] = {0.f, 0.f, 0.f, 0.f};
    float cv[16];
    #pragma unroll
    for (int k = 0; k < 9; ++k) {
        const int dh = k / 3 - 1, dw = k % 3 - 1;
        if ((unsigned)(h + dh) >= 256u) continue;   // wave-uniform
        const bool kill = (dw == -1 && x0 == 0) || (dw == 1 && x0 == 255);
        const int pxe = kill ? p : (p + dh * 256 + dw);
        const ushort* sp = xnh + (size_t)pxe * 64 + cib;
        uint4 ra = *(const uint4*)sp;
        uint4 rb = *(const uint4*)(sp + 8);
        unsigned rr[8] = {ra.x, ra.y, ra.z, ra.w, rb.x, rb.y, rb.z, rb.w};
        if (kill) {
            #pragma unroll
            for (int q = 0; q < 8; ++q) rr[q] = 0;
        }
        float f[16];
        #pragma unroll
        for (int q = 0; q < 8; ++q) {
            f[2 * q]     = __uint_as_float(rr[q] << 16);
            f[2 * q + 1] = __uint_as_float(rr[q] & 0xffff0000u);
        }
        if (k == 4) {
            #pragma unroll
            for (int ci = 0; ci < 16; ++ci) cv[ci] = f[ci];
        }
        #pragma unroll
        for (int ci = 0; ci < 16; ++ci) {
            const float* wp = aue_wt + (cib + ci) * 36 + k * 4;  // uniform -> s_load
            #pragma unroll
            for (int co = 0; co < 4; ++co)
                pa[co] = fmaf(f[ci], wp[co], pa[co]);
        }
    }
    #pragma unroll
    for (int co = 0; co < 4; ++co) pr[co][g][pxg] = pa[co];
    #pragma unroll
    for (int ci = 0; ci < 16; ++ci) cs[pxg][cib + ci] = cv[ci];
    __syncthreads();

    {
        float s = aue_b[g] + pr[g][0][pxg] + pr[g][1][pxg]
                           + pr[g][2][pxg] + pr[g][3][pxg];
        AU[g * P + p] = fast_sigmoid(s);
    }

    float xv[64];
    #pragma unroll
    for (int c = 0; c < 64; ++c) xv[c] = cs[pxg][c];
    float msv = msin[g * P + p];
    float bo  = b4[g];
    float vals[10];
    float s = 0.f;
    #pragma unroll
    for (int t = 0; t < 10; ++t) {
        float a = bo;
        const float* mwp = mw + t * 256 + g * 64;   // uniform -> s_load
        #pragma unroll
        for (int c = 0; c < 64; ++c) a = fmaf(mwp[c], xv[c], a);
        float v = fast_tanh(a) + msv;
        vals[t] = v;
        s += v;
    }
    float m = s * 0.1f;
    MEAN[g * P + p] = m;
    float var = 0.f;
    #pragma unroll
    for (int t = 0; t < 10; ++t) { float d = vals[t] - m; var = fmaf(d, d, var); }
    EU[g * P + p] = var * (1.0f / 9.0f);
}

// ---------------------------------------------------------------------------
// Fused gates: spec (MLP 4->64->64->64, sigmoid) + spat (3x3 conv 4->9 chain).
// Block = 64 px x 4 waves. All waves do spe for their 16-co chunk (h2 via
// LDS); spa's 9 output channels are split across waves {g, g+4, g+8}.
__global__ __launch_bounds__(256) void gates_k(
        const float* __restrict__ U, int flip,
        const float* __restrict__ aw0, const float* __restrict__ ab0,
        const float* __restrict__ aw1, const float* __restrict__ ab1,
        const float* __restrict__ aw2, const float* __restrict__ ab2,
        const float* __restrict__ pw0, const float* __restrict__ pb0,
        const float* __restrict__ pw1t, const float* __restrict__ pb1,
        const float* __restrict__ pw2t, const float* __restrict__ pb2,
        float* __restrict__ spat, float* __restrict__ specn) {
    __shared__ float h2s[64 * 64];
    const int tid = threadIdx.x;
    const int pxg = tid & 63;
    const int g   = __builtin_amdgcn_readfirstlane(tid >> 6);
    const int cb  = g * 16;
    const int p   = blockIdx.x * 64 + pxg;
    const int h = p >> 8, x0 = p & 255;

    // ---- spe ----
    float u[4];
    #pragma unroll
    for (int ci = 0; ci < 4; ++ci) {
        float v = U[ci * P + p];
        u[ci] = flip ? 1.f - v : v;
    }
    float h2[16];
    #pragma unroll
    for (int j = 0; j < 16; ++j) h2[j] = pb1[cb + j];
    #pragma unroll 8
    for (int ci = 0; ci < 64; ++ci) {
        float s = pb0[ci];
        #pragma unroll
        for (int k = 0; k < 4; ++k) s = fmaf(u[k], pw0[ci * 4 + k], s);
        float hv = fmaxf(s, 0.f);
        const float* wr = pw1t + ci * 64 + cb;     // uniform -> s_load
        #pragma unroll
        for (int j = 0; j < 16; ++j) h2[j] = fmaf(hv, wr[j], h2[j]);
    }
    #pragma unroll
    for (int j = 0; j < 16; ++j)
        h2s[(cb + j) * 64 + pxg] = fmaxf(h2[j], 0.f);
    __syncthreads();

    float h3[16];
    #pragma unroll
    for (int j = 0; j < 16; ++j) h3[j] = pb2[cb + j];
    #pragma unroll 8
    for (int ci = 0; ci < 64; ++ci) {
        float hv = h2s[ci * 64 + pxg];
        const float* wr = pw2t + ci * 64 + cb;     // uniform -> s_load
        #pragma unroll
        for (int j = 0; j < 16; ++j) h3[j] = fmaf(hv, wr[j], h3[j]);
    }
    float* dst = specn + (size_t)p * 64 + cb;
    #pragma unroll
    for (int q = 0; q < 4; ++q)
        *(float4*)(dst + 4 * q) = make_float4(fast_sigmoid(h3[4 * q]),
                                              fast_sigmoid(h3[4 * q + 1]),
                                              fast_sigmoid(h3[4 * q + 2]),
                                              fast_sigmoid(h3[4 * q + 3]));

    // ---- spa (this wave's co subset) ----
    float uh[4][9];
    #pragma unroll
    for (int ci = 0; ci < 4; ++ci) {
        const float* up = U + ci * P;
        #pragma unroll
        for (int kh = 0; kh < 3; ++kh) {
            int hh = h + kh - 1;
            bool hok = (unsigned)hh < 256u;
            #pragma unroll
            for (int kw = 0; kw < 3; ++kw) {
                int wx = x0 + kw - 1;
                bool ok = hok && (unsigned)wx < 256u;
                float v = ok ? up[hh * WW + wx] : 0.f;
                if (flip && ok) v = 1.f - v;
                uh[ci][kh * 3 + kw] = v;
            }
        }
    }
    float a1[9];
    #pragma unroll
    for (int co = 0; co < 9; ++co) {
        float s = ab0[co];
        #pragma unroll
        for (int ci = 0; ci < 4; ++ci)
            #pragma unroll
            for (int k = 0; k < 9; ++k)
                s = fmaf(uh[ci][k], aw0[co * 36 + ci * 9 + k], s);
        a1[co] = fmaxf(s, 0.f);
    }
    float a2[9];
    #pragma unroll
    for (int co = 0; co < 9; ++co) {
        float s = ab1[co];
        #pragma unroll
        for (int ci = 0; ci < 9; ++ci) s = fmaf(a1[ci], aw1[co * 9 + ci], s);
        a2[co] = fmaxf(s, 0.f);
    }
    #pragma unroll
    for (int cq = 0; cq < 3; ++cq) {
        const int co = g + cq * 4;
        if (co < 9) {
            float s = ab2[co];
            #pragma unroll
            for (int ci = 0; ci < 9; ++ci) s = fmaf(a2[ci], aw2[co * 9 + ci], s);
            spat[co * P + p] = fast_sigmoid(s);
        }
    }
}

// ---------------------------------------------------------------------------
// uaconv v5: MFMA implicit GEMM, 1x1 conv folded into W2 = cw @ Wr.
// OUTMODE 0: f2 NHWC bf16; OUTMODE 1: FOUT f32 CHW. Both +cb, lrelu.
template<int OUTMODE>
__global__ __launch_bounds__(256) void uaconv5_k(
        const ushort* __restrict__ xa, const ushort* __restrict__ xb,
        const float* __restrict__ specn, const float* __restrict__ spat,
        const ushort* __restrict__ w2bf, const float* __restrict__ cb,
        float* __restrict__ outf, ushort* __restrict__ outh) {
    __shared__ float tls[4][16 * 35];
    const int tid  = threadIdx.x;
    const int lane = tid & 63;
    const int wv   = __builtin_amdgcn_readfirstlane(tid >> 6);
    const int lrow = lane & 15;
    const int kg   = lane >> 4;
    const int s    = blockIdx.x * 4 + wv;
    const int row  = s >> 4;
    const int c16  = s & 15;
    const int pb   = s << 4;
    const int px   = pb + lrow;

    float sl[8], sh[8];
    {
        const float* sp = specn + (size_t)px * 64 + kg * 8;
        float4 a = *(const float4*)sp;
        float4 b = *(const float4*)(sp + 4);
        sl[0] = a.x; sl[1] = a.y; sl[2] = a.z; sl[3] = a.w;
        sl[4] = b.x; sl[5] = b.y; sl[6] = b.z; sl[7] = b.w;
        float4 c = *(const float4*)(sp + 32);
        float4 d = *(const float4*)(sp + 36);
        sh[0] = c.x; sh[1] = c.y; sh[2] = c.z; sh[3] = c.w;
        sh[4] = d.x; sh[5] = d.y; sh[6] = d.z; sh[7] = d.w;
    }
    const ushort* b0p = w2bf + lrow * 576 + kg * 8;
    const ushort* b1p = w2bf + (16 + lrow) * 576 + kg * 8;

    f32x4 acc0 = {0.f, 0.f, 0.f, 0.f};
    f32x4 acc1 = {0.f, 0.f, 0.f, 0.f};

    #pragma unroll
    for (int k = 0; k < 9; ++k) {
        const int dh = k / 3 - 1, dw = k % 3 - 1;
        if ((unsigned)(row + dh) >= 256u) continue;   // wave-uniform skip
        const bool kill = (dw == -1 && c16 == 0 && lrow == 0) ||
                          (dw == 1 && c16 == 15 && lrow == 15);
        float stk = spat[k * P + px];
        if (kill) stk = 0.f;
        const int pxe = kill ? px : (px + dh * 256 + dw);
        #pragma unroll
        for (int par = 0; par < 2; ++par) {
            const ushort* src = (par == 0) ? (xa + (size_t)pxe * 32 + kg * 8)
                                           : (xb + (size_t)pxe * 32 + kg * 8);
            uint4 raw = *(const uint4*)src;
            const float* ss = par ? sh : sl;
            unsigned rr[4] = {raw.x, raw.y, raw.z, raw.w};
            union { unsigned u[4]; bf16x8 v; } af;
            #pragma unroll
            for (int q = 0; q < 4; ++q) {
                float e0 = __uint_as_float(rr[q] << 16)          * (ss[2 * q] * stk);
                float e1 = __uint_as_float(rr[q] & 0xffff0000u)  * (ss[2 * q + 1] * stk);
                af.u[q] = pack_bf2(e0, e1);
            }
            const int ki = k * 2 + par;
            bf16x8 bf0 = *(const bf16x8*)(b0p + ki * 32);
            bf16x8 bf1 = *(const bf16x8*)(b1p + ki * 32);
            acc0 = __builtin_amdgcn_mfma_f32_16x16x32_bf16(af.v, bf0, acc0, 0, 0, 0);
            acc1 = __builtin_amdgcn_mfma_f32_16x16x32_bf16(af.v, bf1, acc1, 0, 0, 0);
        }
    }

    const float cb0 = cb[lrow], cb1 = cb[16 + lrow];
    float* tw = tls[wv];
    #pragma unroll
    for (int j = 0; j < 4; ++j) {
        float y0 = acc0[j] + cb0; y0 = y0 > 0.f ? y0 : 0.2f * y0;
        float y1 = acc1[j] + cb1; y1 = y1 > 0.f ? y1 : 0.2f * y1;
        tw[(kg * 4 + j) * 35 + lrow] = y0;
        tw[(kg * 4 + j) * 35 + 16 + lrow] = y1;
    }
    asm volatile("s_waitcnt lgkmcnt(0)" ::: "memory");
    if constexpr (OUTMODE == 0) {
        const float* rp = tw + lrow * 35 + kg * 8;
        unsigned o[4];
        #pragma unroll
        for (int q = 0; q < 4; ++q)
            o[q] = pack_bf2(rp[2 * q], rp[2 * q + 1]);
        *(uint4*)(outh + (size_t)(pb + lrow) * 32 + kg * 8) =
            make_uint4(o[0], o[1], o[2], o[3]);
    } else {
        #pragma unroll
        for (int it = 0; it < 8; ++it) {
            const int mo = kg * 8 + it;
            outf[mo * P + pb + lrow] = tw[lrow * 35 + mo];
        }
    }
    asm volatile("s_waitcnt lgkmcnt(0)" ::: "memory");
}

// ---------------------------------------------------------------------------
extern "C" void kernel_launch(void* const* d_in, const int* in_sizes, int n_in,
                              void* d_out, int out_size, void* d_ws, size_t ws_size,
                              hipStream_t stream) {
    const float* F1        = (const float*)d_in[0];
    const float* ms        = (const float*)d_in[1];
    const float* pan       = (const float*)d_in[2];
    const float* masks_u   = (const float*)d_in[3];
    const float* ue_conv_w = (const float*)d_in[4];
    const float* ue_conv_b = (const float*)d_in[5];
    const float* ue_out_w  = (const float*)d_in[6];
    const float* ue_out_b  = (const float*)d_in[7];
    const float* ue_aue_w  = (const float*)d_in[8];
    const float* ue_aue_b  = (const float*)d_in[9];
    const float* conv1_w   = (const float*)d_in[10];
    const float* conv1_b   = (const float*)d_in[11];
    const float* conv2_w   = (const float*)d_in[12];
    const float* conv2_b   = (const float*)d_in[13];
    const float* spa1_w0 = (const float*)d_in[14];
    const float* spa1_b0 = (const float*)d_in[15];
    const float* spa1_w1 = (const float*)d_in[16];
    const float* spa1_b1 = (const float*)d_in[17];
    const float* spa1_w2 = (const float*)d_in[18];
    const float* spa1_b2 = (const float*)d_in[19];
    const float* spe1_w0 = (const float*)d_in[20];
    const float* spe1_b0 = (const float*)d_in[21];
    const float* spe1_w1 = (const float*)d_in[22];
    const float* spe1_b1 = (const float*)d_in[23];
    const float* spe1_w2 = (const float*)d_in[24];
    const float* spe1_b2 = (const float*)d_in[25];
    const float* ua1_w   = (const float*)d_in[26];
    const float* spa2_w0 = (const float*)d_in[27];
    const float* spa2_b0 = (const float*)d_in[28];
    const float* spa2_w1 = (const float*)d_in[29];
    const float* spa2_b1 = (const float*)d_in[30];
    const float* spa2_w2 = (const float*)d_in[31];
    const float* spa2_b2 = (const float*)d_in[32];
    const float* spe2_w0 = (const float*)d_in[33];
    const float* spe2_b0 = (const float*)d_in[34];
    const float* spe2_w1 = (const float*)d_in[35];
    const float* spe2_b1 = (const float*)d_in[36];
    const float* spe2_w2 = (const float*)d_in[37];
    const float* spe2_b2 = (const float*)d_in[38];
    const float* ua2_w   = (const float*)d_in[39];

    float* out  = (float*)d_out;
    float* AU   = out;             // 4*P
    float* EU   = out + 4 * P;     // 4*P
    float* MEAN = out + 8 * P;     // 4*P
    float* FOUT = out + 12 * P;    // 32*P

    float* ws    = (float*)d_ws;
    float* specn = ws;                          // 64P (NHWC f32)
    float* spat  = ws + 64 * P;                 // 9P
    ushort* xbf   = (ushort*)(ws + 73 * P);     // 32P bf16 (16P f32)
    ushort* panbf = (ushort*)(ws + 89 * P);     // 32P bf16
    ushort* xnh   = (ushort*)(ws + 105 * P);    // 64P bf16 NHWC (32P f32)
    ushort* f2nh  = (ushort*)(ws + 137 * P);    // 32P bf16 (16P f32)
    float* W     = ws + 153 * P;                // 21248 f32 + 27648 f32-equiv
    float* aue_wt = W;
    float* s1w1t  = W + 2304;
    float* s1w2t  = W + 6400;
    float* s2w1t  = W + 10496;
    float* s2w2t  = W + 14592;
    float* mw     = W + 18688;
    ushort* wub   = (ushort*)(W + 21248);
    ushort* wbfu  = wub;
    ushort* w2bf1 = wub + 18432;
    ushort* w2bf2 = wub + 36864;

    dim3 blk(256);

    tobf2_k<<<dim3(512), blk, 0, stream>>>(F1, pan, xbf, panbf);
    prep_k<<<dim3(300), blk, 0, stream>>>(ue_conv_w, ue_aue_w, ua1_w, ua2_w,
                                          spe1_w1, spe1_w2, spe2_w1, spe2_w2,
                                          conv1_w, conv2_w, masks_u, ue_out_w, W, wub);

    // x = conv3x3(F_1; 32->64) via MFMA, NHWC bf16 out
    conv_ue_mfma<<<dim3(1024), blk, 0, stream>>>(xbf, wbfu, ue_conv_b, xnh);
    // Fused head: AU + EU + MEAN
    head_k<<<dim3(1024), blk, 0, stream>>>(xnh, aue_wt, ue_aue_b, mw, ue_out_b, ms,
                                           AU, EU, MEAN);

    // ---- uaconv 1 (U = EU, inputs F1 || pan) + folded conv1 -> f2 bf16 ----
    gates_k<<<dim3(1024), blk, 0, stream>>>(EU, 0,
                                            spa1_w0, spa1_b0, spa1_w1, spa1_b1,
                                            spa1_w2, spa1_b2,
                                            spe1_w0, spe1_b0, s1w1t, spe1_b1,
                                            s1w2t, spe1_b2, spat, specn);
    uaconv5_k<0><<<dim3(1024), blk, 0, stream>>>(xbf, panbf, specn, spat, w2bf1,
                                                 conv1_b, nullptr, f2nh);

    // ---- uaconv 2 (U = 1-EU, inputs F1 || F_2) + folded conv2 -> FOUT ----
    gates_k<<<dim3(1024), blk, 0, stream>>>(EU, 1,
                                            spa2_w0, spa2_b0, spa2_w1, spa2_b1,
                                            spa2_w2, spa2_b2,
                                            spe2_w0, spe2_b0, s2w1t, spe2_b1,
                                            s2w2t, spe2_b2, spat, specn);
    uaconv5_k<1><<<dim3(1024), blk, 0, stream>>>(xbf, f2nh, specn, spat, w2bf2,
                                                 conv2_b, FOUT, nullptr);
}